// Round 8
// baseline (819.646 us; speedup 1.0000x reference)
//
#include <hip/hip_runtime.h>
#include <hip/hip_fp16.h>
#include <cstdint>

#define NEG_SLOPE 0.2f
#define SM_EPS 1e-16f
#define BN_EPS 1e-5f

struct alignas(8) half4v { __half2 lo, hi; };

// ---------- GEMM + fused attention coefficients, 4 rows/thread, fp16 G out ----------
template <int INC, int OUTC, int H>
__global__ __launch_bounds__(256) void gemm_k(const float* __restrict__ A,
                                              const float* __restrict__ W,
                                              const float* __restrict__ asrc,
                                              const float* __restrict__ adst,
                                              __half* __restrict__ G,
                                              float* __restrict__ als,
                                              float* __restrict__ ald, int nrows) {
  constexpr int TPR  = OUTC / 4;   // threads per row (32 or 16)
  constexpr int RS   = 256 / TPR;  // row slots (8 or 16)
  constexpr int ROWS = RS * 4;     // rows per block-iter (4 rows per thread)
  __shared__ float wl[INC * OUTC];
  __shared__ float hl[ROWS * INC];
  for (int i = threadIdx.x * 4; i < INC * OUTC; i += 1024)
    *(float4*)&wl[i] = *(const float4*)&W[i];
  int r  = threadIdx.x / TPR;
  int c0 = (threadIdx.x % TPR) * 4;
  float4 sv = *(const float4*)&asrc[c0];
  float4 dv = *(const float4*)&adst[c0];
  for (int base = blockIdx.x * ROWS; base < nrows; base += gridDim.x * ROWS) {
    __syncthreads();
    int limit = min(ROWS, nrows - base) * INC;
    for (int i = threadIdx.x * 4; i < limit; i += 1024)
      *(float4*)&hl[i] = *(const float4*)&A[(size_t)base * INC + i];
    __syncthreads();
    float acc[4][4];
#pragma unroll
    for (int q = 0; q < 4; q++)
#pragma unroll
      for (int c = 0; c < 4; c++) acc[q][c] = 0.f;
#pragma unroll 8
    for (int k = 0; k < INC; k++) {
      float4 wv = *(float4*)&wl[k * OUTC + c0];
#pragma unroll
      for (int q = 0; q < 4; q++) {
        float h = hl[(r + q * RS) * INC + k];
        acc[q][0] = fmaf(h, wv.x, acc[q][0]);
        acc[q][1] = fmaf(h, wv.y, acc[q][1]);
        acc[q][2] = fmaf(h, wv.z, acc[q][2]);
        acc[q][3] = fmaf(h, wv.w, acc[q][3]);
      }
    }
    float ps[4], pd[4];
#pragma unroll
    for (int q = 0; q < 4; q++) {
      int rq = base + r + q * RS;
      if (rq < nrows) {
        half4v hv;
        hv.lo = __floats2half2_rn(acc[q][0], acc[q][1]);
        hv.hi = __floats2half2_rn(acc[q][2], acc[q][3]);
        *(half4v*)&G[(size_t)rq * OUTC + c0] = hv;
      }
      ps[q] = acc[q][0] * sv.x + acc[q][1] * sv.y + acc[q][2] * sv.z + acc[q][3] * sv.w;
      pd[q] = acc[q][0] * dv.x + acc[q][1] * dv.y + acc[q][2] * dv.z + acc[q][3] * dv.w;
    }
#pragma unroll
    for (int o = 1; o < 16; o <<= 1) {
#pragma unroll
      for (int q = 0; q < 4; q++) {
        ps[q] += __shfl_xor(ps[q], o);
        pd[q] += __shfl_xor(pd[q], o);
      }
    }
    if ((threadIdx.x & 15) == 0) {
      int head = c0 >> 6;
#pragma unroll
      for (int q = 0; q < 4; q++) {
        int rq = base + r + q * RS;
        if (rq < nrows) {
          als[(size_t)rq * H + head] = ps[q];
          ald[(size_t)rq * H + head] = pd[q];
        }
      }
    }
  }
}

// ---------- CSR build ----------
__global__ void deg_k(const int* __restrict__ dst, int E_, int n, int* __restrict__ deg) {
  int ET = E_ + n;
  for (int e = blockIdx.x * blockDim.x + threadIdx.x; e < ET; e += gridDim.x * blockDim.x) {
    int dN = (e < E_) ? dst[e] : (e - E_);
    atomicAdd(&deg[dN], 1);
  }
}

__global__ __launch_bounds__(1024) void scan1_k(const int* __restrict__ deg,
                                                int* __restrict__ incl,
                                                int* __restrict__ bsum, int n) {
  __shared__ int sm[1024];
  int i = blockIdx.x * 1024 + threadIdx.x;
  int v = (i < n) ? deg[i] : 0;
  sm[threadIdx.x] = v;
  __syncthreads();
#pragma unroll
  for (int o = 1; o < 1024; o <<= 1) {
    int t = (threadIdx.x >= o) ? sm[threadIdx.x - o] : 0;
    __syncthreads();
    sm[threadIdx.x] += t;
    __syncthreads();
  }
  if (i < n) incl[i] = sm[threadIdx.x];
  if (threadIdx.x == 1023) bsum[blockIdx.x] = sm[1023];
}

__global__ void scan2_k(int* __restrict__ bsum, int nb) {
  int lane = threadIdx.x;
  int v = (lane < nb) ? bsum[lane] : 0;
#pragma unroll
  for (int o = 1; o < 64; o <<= 1) {
    int t = __shfl_up(v, o);
    if (lane >= o) v += t;
  }
  if (lane < nb) bsum[lane] = v;
}

__global__ void scan3_k(const int* __restrict__ incl, const int* __restrict__ bsum,
                        int* __restrict__ rowptr, int n) {
  int i = blockIdx.x * blockDim.x + threadIdx.x;
  if (i < n) {
    int blk = i >> 10;
    int off = blk ? bsum[blk - 1] : 0;
    rowptr[i + 1] = incl[i] + off;
  }
  if (i == 0) rowptr[0] = 0;
}

// range-partitioned CSR fill + canonicalizing per-segment sort.
// Each block owns a contiguous node range; LDS cursors; writes land only in the
// block's private CSR region. After the fill, each thread insertion-sorts its
// nodes' segments by src id -> CSRSRC content is bit-identical every launch
// regardless of atomic arrival order (determinism required by the harness).
__global__ __launch_bounds__(512) void csr_fill_range_k(
    const int* __restrict__ src, const int* __restrict__ dst, int E_, int n,
    const int* __restrict__ rowptr, uint16_t* __restrict__ csr_src) {
  __shared__ int cur[512];
  int npb = (n + gridDim.x - 1) / gridDim.x;  // nodes per block (<=512)
  int n0  = blockIdx.x * npb;
  int n1  = min(n0 + npb, n);
  if (n0 >= n) return;
  for (int i = threadIdx.x; i < n1 - n0; i += blockDim.x) cur[i] = rowptr[n0 + i];
  __syncthreads();
  int ET = E_ + n;
  for (int e = threadIdx.x; e < ET; e += blockDim.x) {
    int dN = (e < E_) ? dst[e] : (e - E_);
    if (dN >= n0 && dN < n1) {
      int sN = (e < E_) ? src[e] : dN;
      int pos = atomicAdd(&cur[dN - n0], 1);
      csr_src[pos] = (uint16_t)sN;
    }
  }
  __syncthreads();
  // canonical order: ascending src id (duplicates are bit-identical)
  for (int t = threadIdx.x; t < n1 - n0; t += blockDim.x) {
    int beg = rowptr[n0 + t];
    int end = rowptr[n0 + t + 1];
    for (int i = beg + 1; i < end; ++i) {
      uint16_t v = csr_src[i];
      int j = i - 1;
      while (j >= beg && csr_src[j] > v) { csr_src[j + 1] = csr_src[j]; --j; }
      csr_src[j + 1] = v;
    }
  }
}

// ---------- fused GAT aggregation (H=2): 32-lane node groups, fp16 G gather ----------
__global__ __launch_bounds__(256) void gat_agg2_k(
    const int* __restrict__ rowptr, const uint16_t* __restrict__ csr_src,
    const float* __restrict__ als, const float* __restrict__ ald,
    const __half* __restrict__ G, const float* __restrict__ bias,
    const float* __restrict__ gamma, const float* __restrict__ beta,
    const float* __restrict__ mean, const float* __restrict__ var,
    float* __restrict__ out, int n) {
  int l   = threadIdx.x & 31;  // lane within group
  int grp = (blockIdx.x * blockDim.x + threadIdx.x) >> 5;
  int ng  = (gridDim.x * blockDim.x) >> 5;
  bool h1 = (l >= 16);         // lanes 0-15: head 0 (ch 0..63), 16-31: head 1
  int c0  = 4 * l;             // 4 channels per lane
  for (int node = grp; node < n; node += ng) {
    int beg = rowptr[node];
    int deg = rowptr[node + 1] - beg;
    float2 adp = *(const float2*)&ald[(size_t)node * 2];
    float4 accA = make_float4(0.f, 0.f, 0.f, 0.f);
    float4 accB = make_float4(0.f, 0.f, 0.f, 0.f);
    if (deg <= 32) {
      int sl = 0;
      float p0 = 0.f, p1 = 0.f;
      if (l < deg) {
        sl = csr_src[beg + l];
        float2 ap = *(const float2*)&als[(size_t)sl * 2];
        float v0 = ap.x + adp.x, v1 = ap.y + adp.y;
        v0 = v0 > 0.f ? v0 : NEG_SLOPE * v0;
        v1 = v1 > 0.f ? v1 : NEG_SLOPE * v1;
        p0 = __expf(v0); p1 = __expf(v1);
      }
      float s0 = p0, s1 = p1;
#pragma unroll
      for (int o = 1; o < 32; o <<= 1) {
        s0 += __shfl_xor(s0, o, 32);
        s1 += __shfl_xor(s1, o, 32);
      }
      float a0 = p0 / (s0 + SM_EPS);
      float a1 = p1 / (s1 + SM_EPS);
      int i = 0;
      for (; i + 2 <= deg; i += 2) {
        int sA = __shfl(sl, i, 32), sB = __shfl(sl, i + 1, 32);
        float wA0 = __shfl(a0, i, 32),     wA1 = __shfl(a1, i, 32);
        float wB0 = __shfl(a0, i + 1, 32), wB1 = __shfl(a1, i + 1, 32);
        float wA = h1 ? wA1 : wA0;
        float wB = h1 ? wB1 : wB0;
        half4v gA = *(const half4v*)&G[(size_t)sA * 128 + c0];
        half4v gB = *(const half4v*)&G[(size_t)sB * 128 + c0];
        float2 gAl = __half22float2(gA.lo), gAh = __half22float2(gA.hi);
        float2 gBl = __half22float2(gB.lo), gBh = __half22float2(gB.hi);
        accA.x = fmaf(wA, gAl.x, accA.x); accA.y = fmaf(wA, gAl.y, accA.y);
        accA.z = fmaf(wA, gAh.x, accA.z); accA.w = fmaf(wA, gAh.y, accA.w);
        accB.x = fmaf(wB, gBl.x, accB.x); accB.y = fmaf(wB, gBl.y, accB.y);
        accB.z = fmaf(wB, gBh.x, accB.z); accB.w = fmaf(wB, gBh.y, accB.w);
      }
      for (; i < deg; ++i) {
        int   s  = __shfl(sl, i, 32);
        float w0 = __shfl(a0, i, 32), w1 = __shfl(a1, i, 32);
        float w  = h1 ? w1 : w0;
        half4v gv = *(const half4v*)&G[(size_t)s * 128 + c0];
        float2 gl = __half22float2(gv.lo), gh = __half22float2(gv.hi);
        accA.x = fmaf(w, gl.x, accA.x); accA.y = fmaf(w, gl.y, accA.y);
        accA.z = fmaf(w, gh.x, accA.z); accA.w = fmaf(w, gh.y, accA.w);
      }
    } else {
      float s0 = 0.f, s1 = 0.f;
      for (int i = l; i < deg; i += 32) {
        int s = csr_src[beg + i];
        float2 ap = *(const float2*)&als[(size_t)s * 2];
        float v0 = ap.x + adp.x; v0 = v0 > 0.f ? v0 : NEG_SLOPE * v0;
        float v1 = ap.y + adp.y; v1 = v1 > 0.f ? v1 : NEG_SLOPE * v1;
        s0 += __expf(v0); s1 += __expf(v1);
      }
#pragma unroll
      for (int o = 1; o < 32; o <<= 1) {
        s0 += __shfl_xor(s0, o, 32);
        s1 += __shfl_xor(s1, o, 32);
      }
      float inv0 = 1.f / (s0 + SM_EPS);
      float inv1 = 1.f / (s1 + SM_EPS);
      for (int i = 0; i < deg; ++i) {
        int s = csr_src[beg + i];
        float2 ap = *(const float2*)&als[(size_t)s * 2];
        float v0 = ap.x + adp.x; v0 = v0 > 0.f ? v0 : NEG_SLOPE * v0;
        float v1 = ap.y + adp.y; v1 = v1 > 0.f ? v1 : NEG_SLOPE * v1;
        float w = h1 ? (__expf(v1) * inv1) : (__expf(v0) * inv0);
        half4v gv = *(const half4v*)&G[(size_t)s * 128 + c0];
        float2 gl = __half22float2(gv.lo), gh = __half22float2(gv.hi);
        accA.x = fmaf(w, gl.x, accA.x); accA.y = fmaf(w, gl.y, accA.y);
        accA.z = fmaf(w, gh.x, accA.z); accA.w = fmaf(w, gh.y, accA.w);
      }
    }
    float4 acc = make_float4(accA.x + accB.x, accA.y + accB.y,
                             accA.z + accB.z, accA.w + accB.w);
    float4 bv = *(const float4*)&bias[c0];
    float4 mv = *(const float4*)&mean[c0];
    float4 vv = *(const float4*)&var[c0];
    float4 gv = *(const float4*)&gamma[c0];
    float4 tv = *(const float4*)&beta[c0];
    float4 u;
    u.x = fmaxf((acc.x + bv.x - mv.x) * rsqrtf(vv.x + BN_EPS) * gv.x + tv.x, 0.f);
    u.y = fmaxf((acc.y + bv.y - mv.y) * rsqrtf(vv.y + BN_EPS) * gv.y + tv.y, 0.f);
    u.z = fmaxf((acc.z + bv.z - mv.z) * rsqrtf(vv.z + BN_EPS) * gv.z + tv.z, 0.f);
    u.w = fmaxf((acc.w + bv.w - mv.w) * rsqrtf(vv.w + BN_EPS) * gv.w + tv.w, 0.f);
    *(float4*)&out[(size_t)node * 128 + c0] = u;
  }
}

// ---------- GAT aggregation (H=1, final layer): 32-lane groups ----------
__global__ __launch_bounds__(256) void gat_agg1_k(
    const int* __restrict__ rowptr, const uint16_t* __restrict__ csr_src,
    const float* __restrict__ als, const float* __restrict__ ald,
    const __half* __restrict__ G, const float* __restrict__ bias,
    float* __restrict__ out, int n) {
  int l   = threadIdx.x & 31;
  int grp = (blockIdx.x * blockDim.x + threadIdx.x) >> 5;
  int ng  = (gridDim.x * blockDim.x) >> 5;
  int c0  = 2 * l;  // 2 channels per lane (64 ch total)
  for (int node = grp; node < n; node += ng) {
    int beg = rowptr[node];
    int deg = rowptr[node + 1] - beg;
    float ad0 = ald[node];
    float2 accA = make_float2(0.f, 0.f), accB = make_float2(0.f, 0.f);
    if (deg <= 32) {
      int sl = 0;
      float p0 = 0.f;
      if (l < deg) {
        sl = csr_src[beg + l];
        float v0 = als[sl] + ad0;
        v0 = v0 > 0.f ? v0 : NEG_SLOPE * v0;
        p0 = __expf(v0);
      }
      float s0 = p0;
#pragma unroll
      for (int o = 1; o < 32; o <<= 1) s0 += __shfl_xor(s0, o, 32);
      float a0 = p0 / (s0 + SM_EPS);
      int i = 0;
      for (; i + 2 <= deg; i += 2) {
        int sA = __shfl(sl, i, 32), sB = __shfl(sl, i + 1, 32);
        float wA = __shfl(a0, i, 32), wB = __shfl(a0, i + 1, 32);
        float2 gA = __half22float2(*(const __half2*)&G[(size_t)sA * 64 + c0]);
        float2 gB = __half22float2(*(const __half2*)&G[(size_t)sB * 64 + c0]);
        accA.x = fmaf(wA, gA.x, accA.x); accA.y = fmaf(wA, gA.y, accA.y);
        accB.x = fmaf(wB, gB.x, accB.x); accB.y = fmaf(wB, gB.y, accB.y);
      }
      for (; i < deg; ++i) {
        int   s = __shfl(sl, i, 32);
        float w = __shfl(a0, i, 32);
        float2 g2 = __half22float2(*(const __half2*)&G[(size_t)s * 64 + c0]);
        accA.x = fmaf(w, g2.x, accA.x); accA.y = fmaf(w, g2.y, accA.y);
      }
    } else {
      float s0 = 0.f;
      for (int i = l; i < deg; i += 32) {
        int s = csr_src[beg + i];
        float v0 = als[s] + ad0; v0 = v0 > 0.f ? v0 : NEG_SLOPE * v0;
        s0 += __expf(v0);
      }
#pragma unroll
      for (int o = 1; o < 32; o <<= 1) s0 += __shfl_xor(s0, o, 32);
      float inv0 = 1.f / (s0 + SM_EPS);
      for (int i = 0; i < deg; ++i) {
        int s = csr_src[beg + i];
        float v0 = als[s] + ad0; v0 = v0 > 0.f ? v0 : NEG_SLOPE * v0;
        float w = __expf(v0) * inv0;
        float2 g2 = __half22float2(*(const __half2*)&G[(size_t)s * 64 + c0]);
        accA.x = fmaf(w, g2.x, accA.x); accA.y = fmaf(w, g2.y, accA.y);
      }
    }
    float2 bv = *(const float2*)&bias[c0];
    *(float2*)&out[(size_t)node * 64 + c0] =
        make_float2(accA.x + accB.x + bv.x, accA.y + accB.y + bv.y);
  }
}

// =======================================================================
extern "C" void kernel_launch(void* const* d_in, const int* in_sizes, int n_in,
                              void* d_out, int out_size, void* d_ws, size_t ws_size,
                              hipStream_t stream) {
  const float* x   = (const float*)d_in[0];
  const int*   ei  = (const int*)d_in[1];
  const float* W0  = (const float*)d_in[2];
  const float* as0 = (const float*)d_in[3];
  const float* ad0 = (const float*)d_in[4];
  const float* b0  = (const float*)d_in[5];
  const float* gm0 = (const float*)d_in[6];
  const float* bt0 = (const float*)d_in[7];
  const float* mu0 = (const float*)d_in[8];
  const float* vr0 = (const float*)d_in[9];
  const float* W1  = (const float*)d_in[10];
  const float* as1 = (const float*)d_in[11];
  const float* ad1 = (const float*)d_in[12];
  const float* b1  = (const float*)d_in[13];
  const float* gm1 = (const float*)d_in[14];
  const float* bt1 = (const float*)d_in[15];
  const float* mu1 = (const float*)d_in[16];
  const float* vr1 = (const float*)d_in[17];
  const float* W2  = (const float*)d_in[18];
  const float* as2 = (const float*)d_in[19];
  const float* ad2 = (const float*)d_in[20];
  const float* b2  = (const float*)d_in[21];

  int N  = in_sizes[0] / 128;
  int E  = in_sizes[1] / 2;
  int ET = E + N;
  const int* srcp = ei;
  const int* dstp = ei + E;

  char* w = (char*)d_ws;
  auto carve = [&](size_t bytes) {
    void* p = (void*)w;
    w += (bytes + 255) & ~(size_t)255;
    return p;
  };
  __half*   G      = (__half*)carve((size_t)N * 128 * 2);
  float*    Hb     = (float*)carve((size_t)N * 128 * 4);
  float*    ALS    = (float*)carve((size_t)N * 2 * 4);
  float*    ALD    = (float*)carve((size_t)N * 2 * 4);
  int*      DEG    = (int*)carve((size_t)N * 4);
  int*      INCL   = (int*)carve((size_t)N * 4);
  int*      BSUM   = (int*)carve((size_t)64 * 4);
  int*      ROWPTR = (int*)carve((size_t)(N + 1) * 4);
  uint16_t* CSRSRC = (uint16_t*)carve((size_t)ET * 2);

  int egrid = min((ET + 255) / 256, 2048);
  int agrid = (N + 7) / 8;  // 32-lane groups: 8 nodes per 256-thread block
  int nblk  = (N + 1023) / 1024;

  // ---- CSR build (graph shared by all 3 layers) ----
  hipMemsetAsync(DEG, 0, (size_t)N * 4, stream);
  deg_k<<<egrid, 256, 0, stream>>>(dstp, E, N, DEG);
  scan1_k<<<nblk, 1024, 0, stream>>>(DEG, INCL, BSUM, N);
  scan2_k<<<1, 64, 0, stream>>>(BSUM, nblk);
  scan3_k<<<(N + 255) / 256, 256, 0, stream>>>(INCL, BSUM, ROWPTR, N);
  csr_fill_range_k<<<256, 512, 0, stream>>>(srcp, dstp, E, N, ROWPTR, CSRSRC);

  // ---------------- layer 0 ----------------
  gemm_k<128, 128, 2><<<512, 256, 0, stream>>>(x, W0, as0, ad0, G, ALS, ALD, N);
  gat_agg2_k<<<agrid, 256, 0, stream>>>(ROWPTR, CSRSRC, ALS, ALD, G, b0, gm0, bt0,
                                        mu0, vr0, Hb, N);
  // ---------------- layer 1 ----------------
  gemm_k<128, 128, 2><<<512, 256, 0, stream>>>(Hb, W1, as1, ad1, G, ALS, ALD, N);
  gat_agg2_k<<<agrid, 256, 0, stream>>>(ROWPTR, CSRSRC, ALS, ALD, G, b1, gm1, bt1,
                                        mu1, vr1, Hb, N);
  // ---------------- layer 2 ----------------
  gemm_k<128, 64, 1><<<512, 256, 0, stream>>>(Hb, W2, as2, ad2, G, ALS, ALD, N);
  gat_agg1_k<<<agrid, 256, 0, stream>>>(ROWPTR, CSRSRC, ALS, ALD, G, b2,
                                        (float*)d_out, N);
}

// Round 9
// 331.903 us; speedup vs baseline: 2.4695x; 2.4695x over previous
//
#include <hip/hip_runtime.h>
#include <hip/hip_fp16.h>
#include <cstdint>

#define NEG_SLOPE 0.2f
#define SM_EPS 1e-16f
#define BN_EPS 1e-5f

struct alignas(8) half4v { __half2 lo, hi; };

// ---------- GEMM + fused attention coefficients, 4 rows/thread, fp16 G out ----------
template <int INC, int OUTC, int H>
__global__ __launch_bounds__(256) void gemm_k(const float* __restrict__ A,
                                              const float* __restrict__ W,
                                              const float* __restrict__ asrc,
                                              const float* __restrict__ adst,
                                              __half* __restrict__ G,
                                              float* __restrict__ als,
                                              float* __restrict__ ald, int nrows) {
  constexpr int TPR  = OUTC / 4;   // threads per row (32 or 16)
  constexpr int RS   = 256 / TPR;  // row slots (8 or 16)
  constexpr int ROWS = RS * 4;     // rows per block-iter (4 rows per thread)
  __shared__ float wl[INC * OUTC];
  __shared__ float hl[ROWS * INC];
  for (int i = threadIdx.x * 4; i < INC * OUTC; i += 1024)
    *(float4*)&wl[i] = *(const float4*)&W[i];
  int r  = threadIdx.x / TPR;
  int c0 = (threadIdx.x % TPR) * 4;
  float4 sv = *(const float4*)&asrc[c0];
  float4 dv = *(const float4*)&adst[c0];
  for (int base = blockIdx.x * ROWS; base < nrows; base += gridDim.x * ROWS) {
    __syncthreads();
    int limit = min(ROWS, nrows - base) * INC;
    for (int i = threadIdx.x * 4; i < limit; i += 1024)
      *(float4*)&hl[i] = *(const float4*)&A[(size_t)base * INC + i];
    __syncthreads();
    float acc[4][4];
#pragma unroll
    for (int q = 0; q < 4; q++)
#pragma unroll
      for (int c = 0; c < 4; c++) acc[q][c] = 0.f;
#pragma unroll 8
    for (int k = 0; k < INC; k++) {
      float4 wv = *(float4*)&wl[k * OUTC + c0];
#pragma unroll
      for (int q = 0; q < 4; q++) {
        float h = hl[(r + q * RS) * INC + k];
        acc[q][0] = fmaf(h, wv.x, acc[q][0]);
        acc[q][1] = fmaf(h, wv.y, acc[q][1]);
        acc[q][2] = fmaf(h, wv.z, acc[q][2]);
        acc[q][3] = fmaf(h, wv.w, acc[q][3]);
      }
    }
    float ps[4], pd[4];
#pragma unroll
    for (int q = 0; q < 4; q++) {
      int rq = base + r + q * RS;
      if (rq < nrows) {
        half4v hv;
        hv.lo = __floats2half2_rn(acc[q][0], acc[q][1]);
        hv.hi = __floats2half2_rn(acc[q][2], acc[q][3]);
        *(half4v*)&G[(size_t)rq * OUTC + c0] = hv;
      }
      ps[q] = acc[q][0] * sv.x + acc[q][1] * sv.y + acc[q][2] * sv.z + acc[q][3] * sv.w;
      pd[q] = acc[q][0] * dv.x + acc[q][1] * dv.y + acc[q][2] * dv.z + acc[q][3] * dv.w;
    }
#pragma unroll
    for (int o = 1; o < 16; o <<= 1) {
#pragma unroll
      for (int q = 0; q < 4; q++) {
        ps[q] += __shfl_xor(ps[q], o);
        pd[q] += __shfl_xor(pd[q], o);
      }
    }
    if ((threadIdx.x & 15) == 0) {
      int head = c0 >> 6;
#pragma unroll
      for (int q = 0; q < 4; q++) {
        int rq = base + r + q * RS;
        if (rq < nrows) {
          als[(size_t)rq * H + head] = ps[q];
          ald[(size_t)rq * H + head] = pd[q];
        }
      }
    }
  }
}

// ---------- CSR build ----------
__global__ void deg_k(const int* __restrict__ dst, int E_, int n, int* __restrict__ deg) {
  int ET = E_ + n;
  for (int e = blockIdx.x * blockDim.x + threadIdx.x; e < ET; e += gridDim.x * blockDim.x) {
    int dN = (e < E_) ? dst[e] : (e - E_);
    atomicAdd(&deg[dN], 1);
  }
}

__global__ __launch_bounds__(1024) void scan1_k(const int* __restrict__ deg,
                                                int* __restrict__ incl,
                                                int* __restrict__ bsum, int n) {
  __shared__ int sm[1024];
  int i = blockIdx.x * 1024 + threadIdx.x;
  int v = (i < n) ? deg[i] : 0;
  sm[threadIdx.x] = v;
  __syncthreads();
#pragma unroll
  for (int o = 1; o < 1024; o <<= 1) {
    int t = (threadIdx.x >= o) ? sm[threadIdx.x - o] : 0;
    __syncthreads();
    sm[threadIdx.x] += t;
    __syncthreads();
  }
  if (i < n) incl[i] = sm[threadIdx.x];
  if (threadIdx.x == 1023) bsum[blockIdx.x] = sm[1023];
}

__global__ void scan2_k(int* __restrict__ bsum, int nb) {
  int lane = threadIdx.x;
  int v = (lane < nb) ? bsum[lane] : 0;
#pragma unroll
  for (int o = 1; o < 64; o <<= 1) {
    int t = __shfl_up(v, o);
    if (lane >= o) v += t;
  }
  if (lane < nb) bsum[lane] = v;
}

__global__ void scan3_k(const int* __restrict__ incl, const int* __restrict__ bsum,
                        const int* __restrict__ deg, int* __restrict__ rowptr,
                        int* __restrict__ cursor, int n) {
  int i = blockIdx.x * blockDim.x + threadIdx.x;
  if (i < n) {
    int blk = i >> 10;
    int off = blk ? bsum[blk - 1] : 0;
    int r = incl[i] + off;
    rowptr[i + 1] = r;
    cursor[i] = r - deg[i];
  }
  if (i == 0) rowptr[0] = 0;
}

// fast atomic fill (arbitrary segment permutation; canonicalized below)
__global__ void csr_fill_k(const int* __restrict__ src, const int* __restrict__ dst,
                           int E_, int n, int* __restrict__ cursor,
                           uint16_t* __restrict__ csr_src) {
  int ET = E_ + n;
  for (int e = blockIdx.x * blockDim.x + threadIdx.x; e < ET; e += gridDim.x * blockDim.x) {
    int sN = (e < E_) ? src[e] : (e - E_);
    int dN = (e < E_) ? dst[e] : (e - E_);
    int pos = atomicAdd(&cursor[dN], 1);
    csr_src[pos] = (uint16_t)sN;
  }
}

// canonicalize: in-place rank-permutation sort of each dst segment by src id.
// One 32-lane group per node. rank = #{v_j < v_i} + #{v_j==v_i && j<i} is a
// bijection; sorted content is unique regardless of the atomic fill's arrival
// order -> bit-identical CSR (and output) on every launch. Safe in-place: a
// wave's reads all retire before its write loop (lockstep), segments disjoint.
__global__ __launch_bounds__(256) void csr_canon_k(const int* __restrict__ rowptr,
                                                   uint16_t* __restrict__ csr, int n) {
  int l   = threadIdx.x & 31;
  int grp = (blockIdx.x * blockDim.x + threadIdx.x) >> 5;
  int ng  = (gridDim.x * blockDim.x) >> 5;
  for (int node = grp; node < n; node += ng) {
    int beg = rowptr[node];
    int deg = rowptr[node + 1] - beg;
    if (deg <= 1) continue;
    if (deg <= 128) {
      int iters = (deg + 31) >> 5;
      uint16_t v[4];
      int      rk[4];
#pragma unroll
      for (int m = 0; m < 4; m++) {
        if (m >= iters) break;
        int  i   = l + m * 32;
        bool act = i < deg;
        uint16_t vi = act ? csr[beg + i] : (uint16_t)0;
        int rank = 0;
        for (int j = 0; j < deg; j++) {
          uint16_t vj = csr[beg + j];
          rank += (int)((vj < vi) | ((vj == vi) & (j < i)));
        }
        v[m]  = vi;
        rk[m] = act ? rank : -1;
      }
#pragma unroll
      for (int m = 0; m < 4; m++) {
        if (m >= iters) break;
        if (rk[m] >= 0) csr[beg + rk[m]] = v[m];
      }
    } else if (l == 0) {
      // pathological fallback (never expected at Poisson(17))
      for (int i = beg + 1; i < beg + deg; ++i) {
        uint16_t vv = csr[i];
        int j = i - 1;
        while (j >= beg && csr[j] > vv) { csr[j + 1] = csr[j]; --j; }
        csr[j + 1] = vv;
      }
    }
  }
}

// ---------- fused GAT aggregation (H=2): 32-lane node groups, fp16 G gather ----------
__global__ __launch_bounds__(256) void gat_agg2_k(
    const int* __restrict__ rowptr, const uint16_t* __restrict__ csr_src,
    const float* __restrict__ als, const float* __restrict__ ald,
    const __half* __restrict__ G, const float* __restrict__ bias,
    const float* __restrict__ gamma, const float* __restrict__ beta,
    const float* __restrict__ mean, const float* __restrict__ var,
    float* __restrict__ out, int n) {
  int l   = threadIdx.x & 31;  // lane within group
  int grp = (blockIdx.x * blockDim.x + threadIdx.x) >> 5;
  int ng  = (gridDim.x * blockDim.x) >> 5;
  bool h1 = (l >= 16);         // lanes 0-15: head 0 (ch 0..63), 16-31: head 1
  int c0  = 4 * l;             // 4 channels per lane
  for (int node = grp; node < n; node += ng) {
    int beg = rowptr[node];
    int deg = rowptr[node + 1] - beg;
    float2 adp = *(const float2*)&ald[(size_t)node * 2];
    float4 accA = make_float4(0.f, 0.f, 0.f, 0.f);
    float4 accB = make_float4(0.f, 0.f, 0.f, 0.f);
    if (deg <= 32) {
      int sl = 0;
      float p0 = 0.f, p1 = 0.f;
      if (l < deg) {
        sl = csr_src[beg + l];
        float2 ap = *(const float2*)&als[(size_t)sl * 2];
        float v0 = ap.x + adp.x, v1 = ap.y + adp.y;
        v0 = v0 > 0.f ? v0 : NEG_SLOPE * v0;
        v1 = v1 > 0.f ? v1 : NEG_SLOPE * v1;
        p0 = __expf(v0); p1 = __expf(v1);
      }
      float s0 = p0, s1 = p1;
#pragma unroll
      for (int o = 1; o < 32; o <<= 1) {
        s0 += __shfl_xor(s0, o, 32);
        s1 += __shfl_xor(s1, o, 32);
      }
      float a0 = p0 / (s0 + SM_EPS);
      float a1 = p1 / (s1 + SM_EPS);
      int i = 0;
      for (; i + 2 <= deg; i += 2) {
        int sA = __shfl(sl, i, 32), sB = __shfl(sl, i + 1, 32);
        float wA0 = __shfl(a0, i, 32),     wA1 = __shfl(a1, i, 32);
        float wB0 = __shfl(a0, i + 1, 32), wB1 = __shfl(a1, i + 1, 32);
        float wA = h1 ? wA1 : wA0;
        float wB = h1 ? wB1 : wB0;
        half4v gA = *(const half4v*)&G[(size_t)sA * 128 + c0];
        half4v gB = *(const half4v*)&G[(size_t)sB * 128 + c0];
        float2 gAl = __half22float2(gA.lo), gAh = __half22float2(gA.hi);
        float2 gBl = __half22float2(gB.lo), gBh = __half22float2(gB.hi);
        accA.x = fmaf(wA, gAl.x, accA.x); accA.y = fmaf(wA, gAl.y, accA.y);
        accA.z = fmaf(wA, gAh.x, accA.z); accA.w = fmaf(wA, gAh.y, accA.w);
        accB.x = fmaf(wB, gBl.x, accB.x); accB.y = fmaf(wB, gBl.y, accB.y);
        accB.z = fmaf(wB, gBh.x, accB.z); accB.w = fmaf(wB, gBh.y, accB.w);
      }
      for (; i < deg; ++i) {
        int   s  = __shfl(sl, i, 32);
        float w0 = __shfl(a0, i, 32), w1 = __shfl(a1, i, 32);
        float w  = h1 ? w1 : w0;
        half4v gv = *(const half4v*)&G[(size_t)s * 128 + c0];
        float2 gl = __half22float2(gv.lo), gh = __half22float2(gv.hi);
        accA.x = fmaf(w, gl.x, accA.x); accA.y = fmaf(w, gl.y, accA.y);
        accA.z = fmaf(w, gh.x, accA.z); accA.w = fmaf(w, gh.y, accA.w);
      }
    } else {
      float s0 = 0.f, s1 = 0.f;
      for (int i = l; i < deg; i += 32) {
        int s = csr_src[beg + i];
        float2 ap = *(const float2*)&als[(size_t)s * 2];
        float v0 = ap.x + adp.x; v0 = v0 > 0.f ? v0 : NEG_SLOPE * v0;
        float v1 = ap.y + adp.y; v1 = v1 > 0.f ? v1 : NEG_SLOPE * v1;
        s0 += __expf(v0); s1 += __expf(v1);
      }
#pragma unroll
      for (int o = 1; o < 32; o <<= 1) {
        s0 += __shfl_xor(s0, o, 32);
        s1 += __shfl_xor(s1, o, 32);
      }
      float inv0 = 1.f / (s0 + SM_EPS);
      float inv1 = 1.f / (s1 + SM_EPS);
      for (int i = 0; i < deg; ++i) {
        int s = csr_src[beg + i];
        float2 ap = *(const float2*)&als[(size_t)s * 2];
        float v0 = ap.x + adp.x; v0 = v0 > 0.f ? v0 : NEG_SLOPE * v0;
        float v1 = ap.y + adp.y; v1 = v1 > 0.f ? v1 : NEG_SLOPE * v1;
        float w = h1 ? (__expf(v1) * inv1) : (__expf(v0) * inv0);
        half4v gv = *(const half4v*)&G[(size_t)s * 128 + c0];
        float2 gl = __half22float2(gv.lo), gh = __half22float2(gv.hi);
        accA.x = fmaf(w, gl.x, accA.x); accA.y = fmaf(w, gl.y, accA.y);
        accA.z = fmaf(w, gh.x, accA.z); accA.w = fmaf(w, gh.y, accA.w);
      }
    }
    float4 acc = make_float4(accA.x + accB.x, accA.y + accB.y,
                             accA.z + accB.z, accA.w + accB.w);
    float4 bv = *(const float4*)&bias[c0];
    float4 mv = *(const float4*)&mean[c0];
    float4 vv = *(const float4*)&var[c0];
    float4 gv = *(const float4*)&gamma[c0];
    float4 tv = *(const float4*)&beta[c0];
    float4 u;
    u.x = fmaxf((acc.x + bv.x - mv.x) * rsqrtf(vv.x + BN_EPS) * gv.x + tv.x, 0.f);
    u.y = fmaxf((acc.y + bv.y - mv.y) * rsqrtf(vv.y + BN_EPS) * gv.y + tv.y, 0.f);
    u.z = fmaxf((acc.z + bv.z - mv.z) * rsqrtf(vv.z + BN_EPS) * gv.z + tv.z, 0.f);
    u.w = fmaxf((acc.w + bv.w - mv.w) * rsqrtf(vv.w + BN_EPS) * gv.w + tv.w, 0.f);
    *(float4*)&out[(size_t)node * 128 + c0] = u;
  }
}

// ---------- GAT aggregation (H=1, final layer): 32-lane groups ----------
__global__ __launch_bounds__(256) void gat_agg1_k(
    const int* __restrict__ rowptr, const uint16_t* __restrict__ csr_src,
    const float* __restrict__ als, const float* __restrict__ ald,
    const __half* __restrict__ G, const float* __restrict__ bias,
    float* __restrict__ out, int n) {
  int l   = threadIdx.x & 31;
  int grp = (blockIdx.x * blockDim.x + threadIdx.x) >> 5;
  int ng  = (gridDim.x * blockDim.x) >> 5;
  int c0  = 2 * l;  // 2 channels per lane (64 ch total)
  for (int node = grp; node < n; node += ng) {
    int beg = rowptr[node];
    int deg = rowptr[node + 1] - beg;
    float ad0 = ald[node];
    float2 accA = make_float2(0.f, 0.f), accB = make_float2(0.f, 0.f);
    if (deg <= 32) {
      int sl = 0;
      float p0 = 0.f;
      if (l < deg) {
        sl = csr_src[beg + l];
        float v0 = als[sl] + ad0;
        v0 = v0 > 0.f ? v0 : NEG_SLOPE * v0;
        p0 = __expf(v0);
      }
      float s0 = p0;
#pragma unroll
      for (int o = 1; o < 32; o <<= 1) s0 += __shfl_xor(s0, o, 32);
      float a0 = p0 / (s0 + SM_EPS);
      int i = 0;
      for (; i + 2 <= deg; i += 2) {
        int sA = __shfl(sl, i, 32), sB = __shfl(sl, i + 1, 32);
        float wA = __shfl(a0, i, 32), wB = __shfl(a0, i + 1, 32);
        float2 gA = __half22float2(*(const __half2*)&G[(size_t)sA * 64 + c0]);
        float2 gB = __half22float2(*(const __half2*)&G[(size_t)sB * 64 + c0]);
        accA.x = fmaf(wA, gA.x, accA.x); accA.y = fmaf(wA, gA.y, accA.y);
        accB.x = fmaf(wB, gB.x, accB.x); accB.y = fmaf(wB, gB.y, accB.y);
      }
      for (; i < deg; ++i) {
        int   s = __shfl(sl, i, 32);
        float w = __shfl(a0, i, 32);
        float2 g2 = __half22float2(*(const __half2*)&G[(size_t)s * 64 + c0]);
        accA.x = fmaf(w, g2.x, accA.x); accA.y = fmaf(w, g2.y, accA.y);
      }
    } else {
      float s0 = 0.f;
      for (int i = l; i < deg; i += 32) {
        int s = csr_src[beg + i];
        float v0 = als[s] + ad0; v0 = v0 > 0.f ? v0 : NEG_SLOPE * v0;
        s0 += __expf(v0);
      }
#pragma unroll
      for (int o = 1; o < 32; o <<= 1) s0 += __shfl_xor(s0, o, 32);
      float inv0 = 1.f / (s0 + SM_EPS);
      for (int i = 0; i < deg; ++i) {
        int s = csr_src[beg + i];
        float v0 = als[s] + ad0; v0 = v0 > 0.f ? v0 : NEG_SLOPE * v0;
        float w = __expf(v0) * inv0;
        float2 g2 = __half22float2(*(const __half2*)&G[(size_t)s * 64 + c0]);
        accA.x = fmaf(w, g2.x, accA.x); accA.y = fmaf(w, g2.y, accA.y);
      }
    }
    float2 bv = *(const float2*)&bias[c0];
    *(float2*)&out[(size_t)node * 64 + c0] =
        make_float2(accA.x + accB.x + bv.x, accA.y + accB.y + bv.y);
  }
}

// =======================================================================
extern "C" void kernel_launch(void* const* d_in, const int* in_sizes, int n_in,
                              void* d_out, int out_size, void* d_ws, size_t ws_size,
                              hipStream_t stream) {
  const float* x   = (const float*)d_in[0];
  const int*   ei  = (const int*)d_in[1];
  const float* W0  = (const float*)d_in[2];
  const float* as0 = (const float*)d_in[3];
  const float* ad0 = (const float*)d_in[4];
  const float* b0  = (const float*)d_in[5];
  const float* gm0 = (const float*)d_in[6];
  const float* bt0 = (const float*)d_in[7];
  const float* mu0 = (const float*)d_in[8];
  const float* vr0 = (const float*)d_in[9];
  const float* W1  = (const float*)d_in[10];
  const float* as1 = (const float*)d_in[11];
  const float* ad1 = (const float*)d_in[12];
  const float* b1  = (const float*)d_in[13];
  const float* gm1 = (const float*)d_in[14];
  const float* bt1 = (const float*)d_in[15];
  const float* mu1 = (const float*)d_in[16];
  const float* vr1 = (const float*)d_in[17];
  const float* W2  = (const float*)d_in[18];
  const float* as2 = (const float*)d_in[19];
  const float* ad2 = (const float*)d_in[20];
  const float* b2  = (const float*)d_in[21];

  int N  = in_sizes[0] / 128;
  int E  = in_sizes[1] / 2;
  int ET = E + N;
  const int* srcp = ei;
  const int* dstp = ei + E;

  char* w = (char*)d_ws;
  auto carve = [&](size_t bytes) {
    void* p = (void*)w;
    w += (bytes + 255) & ~(size_t)255;
    return p;
  };
  __half*   G      = (__half*)carve((size_t)N * 128 * 2);
  float*    Hb     = (float*)carve((size_t)N * 128 * 4);
  float*    ALS    = (float*)carve((size_t)N * 2 * 4);
  float*    ALD    = (float*)carve((size_t)N * 2 * 4);
  int*      DEG    = (int*)carve((size_t)N * 4);
  int*      INCL   = (int*)carve((size_t)N * 4);
  int*      BSUM   = (int*)carve((size_t)64 * 4);
  int*      ROWPTR = (int*)carve((size_t)(N + 1) * 4);
  int*      CURSOR = (int*)carve((size_t)N * 4);
  uint16_t* CSRSRC = (uint16_t*)carve((size_t)ET * 2);

  int egrid = min((ET + 255) / 256, 2048);
  int agrid = (N + 7) / 8;  // 32-lane groups: 8 nodes per 256-thread block
  int nblk  = (N + 1023) / 1024;

  // ---- CSR build (graph shared by all 3 layers) ----
  hipMemsetAsync(DEG, 0, (size_t)N * 4, stream);
  deg_k<<<egrid, 256, 0, stream>>>(dstp, E, N, DEG);
  scan1_k<<<nblk, 1024, 0, stream>>>(DEG, INCL, BSUM, N);
  scan2_k<<<1, 64, 0, stream>>>(BSUM, nblk);
  scan3_k<<<(N + 255) / 256, 256, 0, stream>>>(INCL, BSUM, DEG, ROWPTR, CURSOR, N);
  csr_fill_k<<<egrid, 256, 0, stream>>>(srcp, dstp, E, N, CURSOR, CSRSRC);
  csr_canon_k<<<agrid, 256, 0, stream>>>(ROWPTR, CSRSRC, N);

  // ---------------- layer 0 ----------------
  gemm_k<128, 128, 2><<<512, 256, 0, stream>>>(x, W0, as0, ad0, G, ALS, ALD, N);
  gat_agg2_k<<<agrid, 256, 0, stream>>>(ROWPTR, CSRSRC, ALS, ALD, G, b0, gm0, bt0,
                                        mu0, vr0, Hb, N);
  // ---------------- layer 1 ----------------
  gemm_k<128, 128, 2><<<512, 256, 0, stream>>>(Hb, W1, as1, ad1, G, ALS, ALD, N);
  gat_agg2_k<<<agrid, 256, 0, stream>>>(ROWPTR, CSRSRC, ALS, ALD, G, b1, gm1, bt1,
                                        mu1, vr1, Hb, N);
  // ---------------- layer 2 ----------------
  gemm_k<128, 64, 1><<<512, 256, 0, stream>>>(Hb, W2, as2, ad2, G, ALS, ALD, N);
  gat_agg1_k<<<agrid, 256, 0, stream>>>(ROWPTR, CSRSRC, ALS, ALD, G, b2,
                                        (float*)d_out, N);
}

// Round 10
// 315.656 us; speedup vs baseline: 2.5966x; 1.0515x over previous
//
#include <hip/hip_runtime.h>
#include <hip/hip_fp16.h>
#include <cstdint>

#define NEG_SLOPE 0.2f
#define SM_EPS 1e-16f
#define BN_EPS 1e-5f

struct alignas(8)  half4v { __half2 lo, hi; };
struct alignas(16) half8v { __half2 h0, h1, h2, h3; };

__device__ __forceinline__ void fma8(float* acc, const half8v& g, float w) {
  float2 f0 = __half22float2(g.h0), f1 = __half22float2(g.h1);
  float2 f2 = __half22float2(g.h2), f3 = __half22float2(g.h3);
  acc[0] = fmaf(w, f0.x, acc[0]); acc[1] = fmaf(w, f0.y, acc[1]);
  acc[2] = fmaf(w, f1.x, acc[2]); acc[3] = fmaf(w, f1.y, acc[3]);
  acc[4] = fmaf(w, f2.x, acc[4]); acc[5] = fmaf(w, f2.y, acc[5]);
  acc[6] = fmaf(w, f3.x, acc[6]); acc[7] = fmaf(w, f3.y, acc[7]);
}

// ---------- GEMM + fused attention coefficients, 4 rows/thread, fp16 G out ----------
template <int INC, int OUTC, int H>
__global__ __launch_bounds__(256) void gemm_k(const float* __restrict__ A,
                                              const float* __restrict__ W,
                                              const float* __restrict__ asrc,
                                              const float* __restrict__ adst,
                                              __half* __restrict__ G,
                                              float* __restrict__ als,
                                              float* __restrict__ ald, int nrows) {
  constexpr int TPR  = OUTC / 4;
  constexpr int RS   = 256 / TPR;
  constexpr int ROWS = RS * 4;
  __shared__ float wl[INC * OUTC];
  __shared__ float hl[ROWS * INC];
  for (int i = threadIdx.x * 4; i < INC * OUTC; i += 1024)
    *(float4*)&wl[i] = *(const float4*)&W[i];
  int r  = threadIdx.x / TPR;
  int c0 = (threadIdx.x % TPR) * 4;
  float4 sv = *(const float4*)&asrc[c0];
  float4 dv = *(const float4*)&adst[c0];
  for (int base = blockIdx.x * ROWS; base < nrows; base += gridDim.x * ROWS) {
    __syncthreads();
    int limit = min(ROWS, nrows - base) * INC;
    for (int i = threadIdx.x * 4; i < limit; i += 1024)
      *(float4*)&hl[i] = *(const float4*)&A[(size_t)base * INC + i];
    __syncthreads();
    float acc[4][4];
#pragma unroll
    for (int q = 0; q < 4; q++)
#pragma unroll
      for (int c = 0; c < 4; c++) acc[q][c] = 0.f;
#pragma unroll 8
    for (int k = 0; k < INC; k++) {
      float4 wv = *(float4*)&wl[k * OUTC + c0];
#pragma unroll
      for (int q = 0; q < 4; q++) {
        float h = hl[(r + q * RS) * INC + k];
        acc[q][0] = fmaf(h, wv.x, acc[q][0]);
        acc[q][1] = fmaf(h, wv.y, acc[q][1]);
        acc[q][2] = fmaf(h, wv.z, acc[q][2]);
        acc[q][3] = fmaf(h, wv.w, acc[q][3]);
      }
    }
    float ps[4], pd[4];
#pragma unroll
    for (int q = 0; q < 4; q++) {
      int rq = base + r + q * RS;
      if (rq < nrows) {
        half4v hv;
        hv.lo = __floats2half2_rn(acc[q][0], acc[q][1]);
        hv.hi = __floats2half2_rn(acc[q][2], acc[q][3]);
        *(half4v*)&G[(size_t)rq * OUTC + c0] = hv;
      }
      ps[q] = acc[q][0] * sv.x + acc[q][1] * sv.y + acc[q][2] * sv.z + acc[q][3] * sv.w;
      pd[q] = acc[q][0] * dv.x + acc[q][1] * dv.y + acc[q][2] * dv.z + acc[q][3] * dv.w;
    }
#pragma unroll
    for (int o = 1; o < 16; o <<= 1) {
#pragma unroll
      for (int q = 0; q < 4; q++) {
        ps[q] += __shfl_xor(ps[q], o);
        pd[q] += __shfl_xor(pd[q], o);
      }
    }
    if ((threadIdx.x & 15) == 0) {
      int head = c0 >> 6;
#pragma unroll
      for (int q = 0; q < 4; q++) {
        int rq = base + r + q * RS;
        if (rq < nrows) {
          als[(size_t)rq * H + head] = ps[q];
          ald[(size_t)rq * H + head] = pd[q];
        }
      }
    }
  }
}

// ---------- CSR build ----------
__global__ void deg_k(const int* __restrict__ dst, int E_, int n, int* __restrict__ deg) {
  int ET = E_ + n;
  for (int e = blockIdx.x * blockDim.x + threadIdx.x; e < ET; e += gridDim.x * blockDim.x) {
    int dN = (e < E_) ? dst[e] : (e - E_);
    atomicAdd(&deg[dN], 1);
  }
}

__global__ __launch_bounds__(1024) void scan1_k(const int* __restrict__ deg,
                                                int* __restrict__ incl,
                                                int* __restrict__ bsum, int n) {
  __shared__ int sm[1024];
  int i = blockIdx.x * 1024 + threadIdx.x;
  int v = (i < n) ? deg[i] : 0;
  sm[threadIdx.x] = v;
  __syncthreads();
#pragma unroll
  for (int o = 1; o < 1024; o <<= 1) {
    int t = (threadIdx.x >= o) ? sm[threadIdx.x - o] : 0;
    __syncthreads();
    sm[threadIdx.x] += t;
    __syncthreads();
  }
  if (i < n) incl[i] = sm[threadIdx.x];
  if (threadIdx.x == 1023) bsum[blockIdx.x] = sm[1023];
}

__global__ void scan2_k(int* __restrict__ bsum, int nb) {
  int lane = threadIdx.x;
  int v = (lane < nb) ? bsum[lane] : 0;
#pragma unroll
  for (int o = 1; o < 64; o <<= 1) {
    int t = __shfl_up(v, o);
    if (lane >= o) v += t;
  }
  if (lane < nb) bsum[lane] = v;
}

__global__ void scan3_k(const int* __restrict__ incl, const int* __restrict__ bsum,
                        const int* __restrict__ deg, int* __restrict__ rowptr,
                        int* __restrict__ cursor, int n) {
  int i = blockIdx.x * blockDim.x + threadIdx.x;
  if (i < n) {
    int blk = i >> 10;
    int off = blk ? bsum[blk - 1] : 0;
    int r = incl[i] + off;
    rowptr[i + 1] = r;
    cursor[i] = r - deg[i];
  }
  if (i == 0) rowptr[0] = 0;
}

__global__ void csr_fill_k(const int* __restrict__ src, const int* __restrict__ dst,
                           int E_, int n, int* __restrict__ cursor,
                           uint16_t* __restrict__ csr_src) {
  int ET = E_ + n;
  for (int e = blockIdx.x * blockDim.x + threadIdx.x; e < ET; e += gridDim.x * blockDim.x) {
    int sN = (e < E_) ? src[e] : (e - E_);
    int dN = (e < E_) ? dst[e] : (e - E_);
    int pos = atomicAdd(&cursor[dN], 1);
    csr_src[pos] = (uint16_t)sN;
  }
}

// canonicalize: in-place rank-permutation sort of each dst segment by src id.
__global__ __launch_bounds__(256) void csr_canon_k(const int* __restrict__ rowptr,
                                                   uint16_t* __restrict__ csr, int n) {
  int l   = threadIdx.x & 31;
  int grp = (blockIdx.x * blockDim.x + threadIdx.x) >> 5;
  int ng  = (gridDim.x * blockDim.x) >> 5;
  for (int node = grp; node < n; node += ng) {
    int beg = rowptr[node];
    int deg = rowptr[node + 1] - beg;
    if (deg <= 1) continue;
    if (deg <= 128) {
      int iters = (deg + 31) >> 5;
      uint16_t v[4];
      int      rk[4];
#pragma unroll
      for (int m = 0; m < 4; m++) {
        if (m >= iters) break;
        int  i   = l + m * 32;
        bool act = i < deg;
        uint16_t vi = act ? csr[beg + i] : (uint16_t)0;
        int rank = 0;
        for (int j = 0; j < deg; j++) {
          uint16_t vj = csr[beg + j];
          rank += (int)((vj < vi) | ((vj == vi) & (j < i)));
        }
        v[m]  = vi;
        rk[m] = act ? rank : -1;
      }
#pragma unroll
      for (int m = 0; m < 4; m++) {
        if (m >= iters) break;
        if (rk[m] >= 0) csr[beg + rk[m]] = v[m];
      }
    } else if (l == 0) {
      for (int i = beg + 1; i < beg + deg; ++i) {
        uint16_t vv = csr[i];
        int j = i - 1;
        while (j >= beg && csr[j] > vv) { csr[j + 1] = csr[j]; --j; }
        csr[j + 1] = vv;
      }
    }
  }
}

// ---------- fused GAT aggregation (H=2): 16 lanes/row, 2 edges per VMEM ----------
__global__ __launch_bounds__(256) void gat_agg2_k(
    const int* __restrict__ rowptr, const uint16_t* __restrict__ csr_src,
    const float* __restrict__ als, const float* __restrict__ ald,
    const __half* __restrict__ G, const float* __restrict__ bias,
    const float* __restrict__ gamma, const float* __restrict__ beta,
    const float* __restrict__ mean, const float* __restrict__ var,
    float* __restrict__ out, int n) {
  int l   = threadIdx.x & 31;
  int grp = (blockIdx.x * blockDim.x + threadIdx.x) >> 5;
  int ng  = (gridDim.x * blockDim.x) >> 5;
  int ehi = l >> 4;        // edge slot within a load-step
  int sub = l & 15;        // 16 lanes cover one 128-ch fp16 row
  int cc  = sub * 8;       // my 8 channels
  bool hh = sub >= 8;      // head of my channels
  for (int node = grp; node < n; node += ng) {
    int beg = rowptr[node];
    int deg = rowptr[node + 1] - beg;
    float2 adp = *(const float2*)&ald[(size_t)node * 2];
    float accP[8], accQ[8];
#pragma unroll
    for (int k = 0; k < 8; k++) { accP[k] = 0.f; accQ[k] = 0.f; }
    if (deg <= 32) {
      int sl_ = 0;
      float p0 = 0.f, p1 = 0.f;
      if (l < deg) {
        sl_ = csr_src[beg + l];
        float2 ap = *(const float2*)&als[(size_t)sl_ * 2];
        float v0 = ap.x + adp.x, v1 = ap.y + adp.y;
        v0 = v0 > 0.f ? v0 : NEG_SLOPE * v0;
        v1 = v1 > 0.f ? v1 : NEG_SLOPE * v1;
        p0 = __expf(v0); p1 = __expf(v1);
      }
      float s0 = p0, s1 = p1;
#pragma unroll
      for (int o = 1; o < 32; o <<= 1) {
        s0 += __shfl_xor(s0, o, 32);
        s1 += __shfl_xor(s1, o, 32);
      }
      float a0 = p0 / (s0 + SM_EPS);   // lanes >= deg have a0 = a1 = 0
      float a1 = p1 / (s1 + SM_EPS);
      for (int i = 0; i < deg; i += 4) {
        int eP = i + ehi;        // edges i, i+1
        int eQ = i + 2 + ehi;    // edges i+2, i+3 (alpha=0 if past deg)
        int sP = __shfl(sl_, eP, 32);
        int sQ = __shfl(sl_, eQ, 32);
        float wP0 = __shfl(a0, eP, 32), wP1 = __shfl(a1, eP, 32);
        float wQ0 = __shfl(a0, eQ, 32), wQ1 = __shfl(a1, eQ, 32);
        float wP = hh ? wP1 : wP0;
        float wQ = hh ? wQ1 : wQ0;
        half8v gP = *(const half8v*)&G[(size_t)sP * 128 + cc];
        half8v gQ = *(const half8v*)&G[(size_t)sQ * 128 + cc];
        fma8(accP, gP, wP);
        fma8(accQ, gQ, wQ);
      }
    } else {
      float s0 = 0.f, s1 = 0.f;
      for (int i = l; i < deg; i += 32) {
        int s = csr_src[beg + i];
        float2 ap = *(const float2*)&als[(size_t)s * 2];
        float v0 = ap.x + adp.x; v0 = v0 > 0.f ? v0 : NEG_SLOPE * v0;
        float v1 = ap.y + adp.y; v1 = v1 > 0.f ? v1 : NEG_SLOPE * v1;
        s0 += __expf(v0); s1 += __expf(v1);
      }
#pragma unroll
      for (int o = 1; o < 32; o <<= 1) {
        s0 += __shfl_xor(s0, o, 32);
        s1 += __shfl_xor(s1, o, 32);
      }
      float inv0 = 1.f / (s0 + SM_EPS);
      float inv1 = 1.f / (s1 + SM_EPS);
      for (int i = 0; i < deg; i += 2) {
        int  e   = i + ehi;
        bool act = e < deg;
        int  sE  = 0;
        float w  = 0.f;
        if (act) {
          sE = csr_src[beg + e];
          float2 ap = *(const float2*)&als[(size_t)sE * 2];
          float v0 = ap.x + adp.x; v0 = v0 > 0.f ? v0 : NEG_SLOPE * v0;
          float v1 = ap.y + adp.y; v1 = v1 > 0.f ? v1 : NEG_SLOPE * v1;
          w = hh ? (__expf(v1) * inv1) : (__expf(v0) * inv0);
        }
        half8v g = *(const half8v*)&G[(size_t)sE * 128 + cc];
        fma8(accP, g, w);
      }
    }
    float o8[8];
#pragma unroll
    for (int k = 0; k < 8; k++) {
      o8[k] = accP[k] + accQ[k];
      o8[k] += __shfl_xor(o8[k], 16, 32);
    }
    if (l < 16) {
      float4 bv0 = *(const float4*)&bias[cc],  bv1 = *(const float4*)&bias[cc + 4];
      float4 mv0 = *(const float4*)&mean[cc],  mv1 = *(const float4*)&mean[cc + 4];
      float4 vv0 = *(const float4*)&var[cc],   vv1 = *(const float4*)&var[cc + 4];
      float4 gv0 = *(const float4*)&gamma[cc], gv1 = *(const float4*)&gamma[cc + 4];
      float4 tv0 = *(const float4*)&beta[cc],  tv1 = *(const float4*)&beta[cc + 4];
      float4 u0, u1;
      u0.x = fmaxf((o8[0] + bv0.x - mv0.x) * rsqrtf(vv0.x + BN_EPS) * gv0.x + tv0.x, 0.f);
      u0.y = fmaxf((o8[1] + bv0.y - mv0.y) * rsqrtf(vv0.y + BN_EPS) * gv0.y + tv0.y, 0.f);
      u0.z = fmaxf((o8[2] + bv0.z - mv0.z) * rsqrtf(vv0.z + BN_EPS) * gv0.z + tv0.z, 0.f);
      u0.w = fmaxf((o8[3] + bv0.w - mv0.w) * rsqrtf(vv0.w + BN_EPS) * gv0.w + tv0.w, 0.f);
      u1.x = fmaxf((o8[4] + bv1.x - mv1.x) * rsqrtf(vv1.x + BN_EPS) * gv1.x + tv1.x, 0.f);
      u1.y = fmaxf((o8[5] + bv1.y - mv1.y) * rsqrtf(vv1.y + BN_EPS) * gv1.y + tv1.y, 0.f);
      u1.z = fmaxf((o8[6] + bv1.z - mv1.z) * rsqrtf(vv1.z + BN_EPS) * gv1.z + tv1.z, 0.f);
      u1.w = fmaxf((o8[7] + bv1.w - mv1.w) * rsqrtf(vv1.w + BN_EPS) * gv1.w + tv1.w, 0.f);
      *(float4*)&out[(size_t)node * 128 + cc]     = u0;
      *(float4*)&out[(size_t)node * 128 + cc + 4] = u1;
    }
  }
}

// ---------- GAT aggregation (H=1): 8 lanes/row, 4 edges per VMEM ----------
__global__ __launch_bounds__(256) void gat_agg1_k(
    const int* __restrict__ rowptr, const uint16_t* __restrict__ csr_src,
    const float* __restrict__ als, const float* __restrict__ ald,
    const __half* __restrict__ G, const float* __restrict__ bias,
    float* __restrict__ out, int n) {
  int l   = threadIdx.x & 31;
  int grp = (blockIdx.x * blockDim.x + threadIdx.x) >> 5;
  int ng  = (gridDim.x * blockDim.x) >> 5;
  int e8  = l >> 3;        // edge slot (0..3)
  int sub = l & 7;         // 8 lanes cover one 64-ch fp16 row
  int cc  = sub * 8;
  for (int node = grp; node < n; node += ng) {
    int beg = rowptr[node];
    int deg = rowptr[node + 1] - beg;
    float ad0 = ald[node];
    float accP[8], accQ[8];
#pragma unroll
    for (int k = 0; k < 8; k++) { accP[k] = 0.f; accQ[k] = 0.f; }
    if (deg <= 32) {
      int sl_ = 0;
      float p0 = 0.f;
      if (l < deg) {
        sl_ = csr_src[beg + l];
        float v0 = als[sl_] + ad0;
        v0 = v0 > 0.f ? v0 : NEG_SLOPE * v0;
        p0 = __expf(v0);
      }
      float s0 = p0;
#pragma unroll
      for (int o = 1; o < 32; o <<= 1) s0 += __shfl_xor(s0, o, 32);
      float a0 = p0 / (s0 + SM_EPS);
      for (int i = 0; i < deg; i += 8) {
        int eP = i + e8;        // edges i..i+3
        int eQ = i + 4 + e8;    // edges i+4..i+7
        int sP = __shfl(sl_, eP, 32);
        int sQ = __shfl(sl_, eQ, 32);
        float wP = __shfl(a0, eP, 32);
        float wQ = __shfl(a0, eQ, 32);
        half8v gP = *(const half8v*)&G[(size_t)sP * 64 + cc];
        half8v gQ = *(const half8v*)&G[(size_t)sQ * 64 + cc];
        fma8(accP, gP, wP);
        fma8(accQ, gQ, wQ);
      }
    } else {
      float s0 = 0.f;
      for (int i = l; i < deg; i += 32) {
        int s = csr_src[beg + i];
        float v0 = als[s] + ad0; v0 = v0 > 0.f ? v0 : NEG_SLOPE * v0;
        s0 += __expf(v0);
      }
#pragma unroll
      for (int o = 1; o < 32; o <<= 1) s0 += __shfl_xor(s0, o, 32);
      float inv0 = 1.f / (s0 + SM_EPS);
      for (int i = 0; i < deg; i += 4) {
        int  e   = i + e8;
        bool act = e < deg;
        int  sE  = 0;
        float w  = 0.f;
        if (act) {
          sE = csr_src[beg + e];
          float v0 = als[sE] + ad0; v0 = v0 > 0.f ? v0 : NEG_SLOPE * v0;
          w = __expf(v0) * inv0;
        }
        half8v g = *(const half8v*)&G[(size_t)sE * 64 + cc];
        fma8(accP, g, w);
      }
    }
    float o8[8];
#pragma unroll
    for (int k = 0; k < 8; k++) {
      o8[k] = accP[k] + accQ[k];
      o8[k] += __shfl_xor(o8[k], 8, 32);
      o8[k] += __shfl_xor(o8[k], 16, 32);
    }
    if (l < 8) {
      float4 bv0 = *(const float4*)&bias[cc], bv1 = *(const float4*)&bias[cc + 4];
      float4 u0 = make_float4(o8[0] + bv0.x, o8[1] + bv0.y, o8[2] + bv0.z, o8[3] + bv0.w);
      float4 u1 = make_float4(o8[4] + bv1.x, o8[5] + bv1.y, o8[6] + bv1.z, o8[7] + bv1.w);
      *(float4*)&out[(size_t)node * 64 + cc]     = u0;
      *(float4*)&out[(size_t)node * 64 + cc + 4] = u1;
    }
  }
}

// =======================================================================
extern "C" void kernel_launch(void* const* d_in, const int* in_sizes, int n_in,
                              void* d_out, int out_size, void* d_ws, size_t ws_size,
                              hipStream_t stream) {
  const float* x   = (const float*)d_in[0];
  const int*   ei  = (const int*)d_in[1];
  const float* W0  = (const float*)d_in[2];
  const float* as0 = (const float*)d_in[3];
  const float* ad0 = (const float*)d_in[4];
  const float* b0  = (const float*)d_in[5];
  const float* gm0 = (const float*)d_in[6];
  const float* bt0 = (const float*)d_in[7];
  const float* mu0 = (const float*)d_in[8];
  const float* vr0 = (const float*)d_in[9];
  const float* W1  = (const float*)d_in[10];
  const float* as1 = (const float*)d_in[11];
  const float* ad1 = (const float*)d_in[12];
  const float* b1  = (const float*)d_in[13];
  const float* gm1 = (const float*)d_in[14];
  const float* bt1 = (const float*)d_in[15];
  const float* mu1 = (const float*)d_in[16];
  const float* vr1 = (const float*)d_in[17];
  const float* W2  = (const float*)d_in[18];
  const float* as2 = (const float*)d_in[19];
  const float* ad2 = (const float*)d_in[20];
  const float* b2  = (const float*)d_in[21];

  int N  = in_sizes[0] / 128;
  int E  = in_sizes[1] / 2;
  int ET = E + N;
  const int* srcp = ei;
  const int* dstp = ei + E;

  char* w = (char*)d_ws;
  auto carve = [&](size_t bytes) {
    void* p = (void*)w;
    w += (bytes + 255) & ~(size_t)255;
    return p;
  };
  __half*   G      = (__half*)carve((size_t)N * 128 * 2);
  float*    Hb     = (float*)carve((size_t)N * 128 * 4);
  float*    ALS    = (float*)carve((size_t)N * 2 * 4);
  float*    ALD    = (float*)carve((size_t)N * 2 * 4);
  int*      DEG    = (int*)carve((size_t)N * 4);
  int*      INCL   = (int*)carve((size_t)N * 4);
  int*      BSUM   = (int*)carve((size_t)64 * 4);
  int*      ROWPTR = (int*)carve((size_t)(N + 1) * 4);
  int*      CURSOR = (int*)carve((size_t)N * 4);
  uint16_t* CSRSRC = (uint16_t*)carve((size_t)ET * 2);

  int egrid = min((ET + 255) / 256, 2048);
  int agrid = (N + 7) / 8;  // 32-lane groups: 8 nodes per 256-thread block
  int nblk  = (N + 1023) / 1024;

  // ---- CSR build (graph shared by all 3 layers) ----
  hipMemsetAsync(DEG, 0, (size_t)N * 4, stream);
  deg_k<<<egrid, 256, 0, stream>>>(dstp, E, N, DEG);
  scan1_k<<<nblk, 1024, 0, stream>>>(DEG, INCL, BSUM, N);
  scan2_k<<<1, 64, 0, stream>>>(BSUM, nblk);
  scan3_k<<<(N + 255) / 256, 256, 0, stream>>>(INCL, BSUM, DEG, ROWPTR, CURSOR, N);
  csr_fill_k<<<egrid, 256, 0, stream>>>(srcp, dstp, E, N, CURSOR, CSRSRC);
  csr_canon_k<<<agrid, 256, 0, stream>>>(ROWPTR, CSRSRC, N);

  // ---------------- layer 0 ----------------
  gemm_k<128, 128, 2><<<512, 256, 0, stream>>>(x, W0, as0, ad0, G, ALS, ALD, N);
  gat_agg2_k<<<agrid, 256, 0, stream>>>(ROWPTR, CSRSRC, ALS, ALD, G, b0, gm0, bt0,
                                        mu0, vr0, Hb, N);
  // ---------------- layer 1 ----------------
  gemm_k<128, 128, 2><<<512, 256, 0, stream>>>(Hb, W1, as1, ad1, G, ALS, ALD, N);
  gat_agg2_k<<<agrid, 256, 0, stream>>>(ROWPTR, CSRSRC, ALS, ALD, G, b1, gm1, bt1,
                                        mu1, vr1, Hb, N);
  // ---------------- layer 2 ----------------
  gemm_k<128, 64, 1><<<512, 256, 0, stream>>>(Hb, W2, as2, ad2, G, ALS, ALD, N);
  gat_agg1_k<<<agrid, 256, 0, stream>>>(ROWPTR, CSRSRC, ALS, ALD, G, b2,
                                        (float*)d_out, N);
}

// Round 11
// 311.532 us; speedup vs baseline: 2.6310x; 1.0132x over previous
//
#include <hip/hip_runtime.h>
#include <hip/hip_fp16.h>
#include <cstdint>

#define NEG_SLOPE 0.2f
#define SM_EPS 1e-16f
#define BN_EPS 1e-5f

struct alignas(8)  half4v { __half2 lo, hi; };
struct alignas(16) half8v { __half2 h0, h1, h2, h3; };

__device__ __forceinline__ void fma8(float* acc, const half8v& g, float w) {
  float2 f0 = __half22float2(g.h0), f1 = __half22float2(g.h1);
  float2 f2 = __half22float2(g.h2), f3 = __half22float2(g.h3);
  acc[0] = fmaf(w, f0.x, acc[0]); acc[1] = fmaf(w, f0.y, acc[1]);
  acc[2] = fmaf(w, f1.x, acc[2]); acc[3] = fmaf(w, f1.y, acc[3]);
  acc[4] = fmaf(w, f2.x, acc[4]); acc[5] = fmaf(w, f2.y, acc[5]);
  acc[6] = fmaf(w, f3.x, acc[6]); acc[7] = fmaf(w, f3.y, acc[7]);
}

// ---------- GEMM + fused attention coefficients, 4 rows/thread, fp16 G out ----------
template <int INC, int OUTC, int H>
__global__ __launch_bounds__(256) void gemm_k(const float* __restrict__ A,
                                              const float* __restrict__ W,
                                              const float* __restrict__ asrc,
                                              const float* __restrict__ adst,
                                              __half* __restrict__ G,
                                              float* __restrict__ als,
                                              float* __restrict__ ald, int nrows) {
  constexpr int TPR  = OUTC / 4;
  constexpr int RS   = 256 / TPR;
  constexpr int ROWS = RS * 4;
  __shared__ float wl[INC * OUTC];
  __shared__ float hl[ROWS * INC];
  for (int i = threadIdx.x * 4; i < INC * OUTC; i += 1024)
    *(float4*)&wl[i] = *(const float4*)&W[i];
  int r  = threadIdx.x / TPR;
  int c0 = (threadIdx.x % TPR) * 4;
  float4 sv = *(const float4*)&asrc[c0];
  float4 dv = *(const float4*)&adst[c0];
  for (int base = blockIdx.x * ROWS; base < nrows; base += gridDim.x * ROWS) {
    __syncthreads();
    int limit = min(ROWS, nrows - base) * INC;
    for (int i = threadIdx.x * 4; i < limit; i += 1024)
      *(float4*)&hl[i] = *(const float4*)&A[(size_t)base * INC + i];
    __syncthreads();
    float acc[4][4];
#pragma unroll
    for (int q = 0; q < 4; q++)
#pragma unroll
      for (int c = 0; c < 4; c++) acc[q][c] = 0.f;
#pragma unroll 8
    for (int k = 0; k < INC; k++) {
      float4 wv = *(float4*)&wl[k * OUTC + c0];
#pragma unroll
      for (int q = 0; q < 4; q++) {
        float h = hl[(r + q * RS) * INC + k];
        acc[q][0] = fmaf(h, wv.x, acc[q][0]);
        acc[q][1] = fmaf(h, wv.y, acc[q][1]);
        acc[q][2] = fmaf(h, wv.z, acc[q][2]);
        acc[q][3] = fmaf(h, wv.w, acc[q][3]);
      }
    }
    float ps[4], pd[4];
#pragma unroll
    for (int q = 0; q < 4; q++) {
      int rq = base + r + q * RS;
      if (rq < nrows) {
        half4v hv;
        hv.lo = __floats2half2_rn(acc[q][0], acc[q][1]);
        hv.hi = __floats2half2_rn(acc[q][2], acc[q][3]);
        *(half4v*)&G[(size_t)rq * OUTC + c0] = hv;
      }
      ps[q] = acc[q][0] * sv.x + acc[q][1] * sv.y + acc[q][2] * sv.z + acc[q][3] * sv.w;
      pd[q] = acc[q][0] * dv.x + acc[q][1] * dv.y + acc[q][2] * dv.z + acc[q][3] * dv.w;
    }
#pragma unroll
    for (int o = 1; o < 16; o <<= 1) {
#pragma unroll
      for (int q = 0; q < 4; q++) {
        ps[q] += __shfl_xor(ps[q], o);
        pd[q] += __shfl_xor(pd[q], o);
      }
    }
    if ((threadIdx.x & 15) == 0) {
      int head = c0 >> 6;
#pragma unroll
      for (int q = 0; q < 4; q++) {
        int rq = base + r + q * RS;
        if (rq < nrows) {
          als[(size_t)rq * H + head] = ps[q];
          ald[(size_t)rq * H + head] = pd[q];
        }
      }
    }
  }
}

// ---------- CSR build ----------
__global__ void deg_k(const int* __restrict__ dst, int E_, int n, int* __restrict__ deg) {
  int ET = E_ + n;
  for (int e = blockIdx.x * blockDim.x + threadIdx.x; e < ET; e += gridDim.x * blockDim.x) {
    int dN = (e < E_) ? dst[e] : (e - E_);
    atomicAdd(&deg[dN], 1);
  }
}

__global__ __launch_bounds__(1024) void scan1_k(const int* __restrict__ deg,
                                                int* __restrict__ incl,
                                                int* __restrict__ bsum, int n) {
  __shared__ int sm[1024];
  int i = blockIdx.x * 1024 + threadIdx.x;
  int v = (i < n) ? deg[i] : 0;
  sm[threadIdx.x] = v;
  __syncthreads();
#pragma unroll
  for (int o = 1; o < 1024; o <<= 1) {
    int t = (threadIdx.x >= o) ? sm[threadIdx.x - o] : 0;
    __syncthreads();
    sm[threadIdx.x] += t;
    __syncthreads();
  }
  if (i < n) incl[i] = sm[threadIdx.x];
  if (threadIdx.x == 1023) bsum[blockIdx.x] = sm[1023];
}

__global__ void scan2_k(int* __restrict__ bsum, int nb) {
  int lane = threadIdx.x;
  int v = (lane < nb) ? bsum[lane] : 0;
#pragma unroll
  for (int o = 1; o < 64; o <<= 1) {
    int t = __shfl_up(v, o);
    if (lane >= o) v += t;
  }
  if (lane < nb) bsum[lane] = v;
}

__global__ void scan3_k(const int* __restrict__ incl, const int* __restrict__ bsum,
                        const int* __restrict__ deg, int* __restrict__ rowptr,
                        int* __restrict__ cursor, int n) {
  int i = blockIdx.x * blockDim.x + threadIdx.x;
  if (i < n) {
    int blk = i >> 10;
    int off = blk ? bsum[blk - 1] : 0;
    int r = incl[i] + off;
    rowptr[i + 1] = r;
    cursor[i] = r - deg[i];
  }
  if (i == 0) rowptr[0] = 0;
}

__global__ void csr_fill_k(const int* __restrict__ src, const int* __restrict__ dst,
                           int E_, int n, int* __restrict__ cursor,
                           uint16_t* __restrict__ csr_src) {
  int ET = E_ + n;
  for (int e = blockIdx.x * blockDim.x + threadIdx.x; e < ET; e += gridDim.x * blockDim.x) {
    int sN = (e < E_) ? src[e] : (e - E_);
    int dN = (e < E_) ? dst[e] : (e - E_);
    int pos = atomicAdd(&cursor[dN], 1);
    csr_src[pos] = (uint16_t)sN;
  }
}

// canonicalize: in-place rank-permutation sort of each dst segment by src id.
__global__ __launch_bounds__(256) void csr_canon_k(const int* __restrict__ rowptr,
                                                   uint16_t* __restrict__ csr, int n) {
  int l   = threadIdx.x & 31;
  int grp = (blockIdx.x * blockDim.x + threadIdx.x) >> 5;
  int ng  = (gridDim.x * blockDim.x) >> 5;
  for (int node = grp; node < n; node += ng) {
    int beg = rowptr[node];
    int deg = rowptr[node + 1] - beg;
    if (deg <= 1) continue;
    if (deg <= 128) {
      int iters = (deg + 31) >> 5;
      uint16_t v[4];
      int      rk[4];
#pragma unroll
      for (int m = 0; m < 4; m++) {
        if (m >= iters) break;
        int  i   = l + m * 32;
        bool act = i < deg;
        uint16_t vi = act ? csr[beg + i] : (uint16_t)0;
        int rank = 0;
        for (int j = 0; j < deg; j++) {
          uint16_t vj = csr[beg + j];
          rank += (int)((vj < vi) | ((vj == vi) & (j < i)));
        }
        v[m]  = vi;
        rk[m] = act ? rank : -1;
      }
#pragma unroll
      for (int m = 0; m < 4; m++) {
        if (m >= iters) break;
        if (rk[m] >= 0) csr[beg + rk[m]] = v[m];
      }
    } else if (l == 0) {
      for (int i = beg + 1; i < beg + deg; ++i) {
        uint16_t vv = csr[i];
        int j = i - 1;
        while (j >= beg && csr[j] > vv) { csr[j + 1] = csr[j]; --j; }
        csr[j + 1] = vv;
      }
    }
  }
}

// ---------- fused GAT aggregation (H=2): 16 lanes/row, 4 row-loads in flight ----------
__global__ __launch_bounds__(256) void gat_agg2_k(
    const int* __restrict__ rowptr, const uint16_t* __restrict__ csr_src,
    const float* __restrict__ als, const float* __restrict__ ald,
    const __half* __restrict__ G, const float* __restrict__ bias,
    const float* __restrict__ gamma, const float* __restrict__ beta,
    const float* __restrict__ mean, const float* __restrict__ var,
    float* __restrict__ out, int n) {
  int l   = threadIdx.x & 31;
  int grp = (blockIdx.x * blockDim.x + threadIdx.x) >> 5;
  int ng  = (gridDim.x * blockDim.x) >> 5;
  int ehi = l >> 4;        // edge slot within a pair
  int sub = l & 15;        // 16 lanes cover one 128-ch fp16 row
  int cc  = sub * 8;       // my 8 channels
  bool hh = sub >= 8;      // head of my channels
  for (int node = grp; node < n; node += ng) {
    int beg = rowptr[node];
    int deg = rowptr[node + 1] - beg;
    float2 adp = *(const float2*)&ald[(size_t)node * 2];
    float accP[8], accQ[8];
#pragma unroll
    for (int k = 0; k < 8; k++) { accP[k] = 0.f; accQ[k] = 0.f; }
    if (deg <= 32) {
      int sl_ = 0;
      float p0 = 0.f, p1 = 0.f;
      if (l < deg) {
        sl_ = csr_src[beg + l];
        float2 ap = *(const float2*)&als[(size_t)sl_ * 2];
        float v0 = ap.x + adp.x, v1 = ap.y + adp.y;
        v0 = v0 > 0.f ? v0 : NEG_SLOPE * v0;
        v1 = v1 > 0.f ? v1 : NEG_SLOPE * v1;
        p0 = __expf(v0); p1 = __expf(v1);
      }
      float s0 = p0, s1 = p1;
#pragma unroll
      for (int o = 1; o < 32; o <<= 1) {
        s0 += __shfl_xor(s0, o, 32);
        s1 += __shfl_xor(s1, o, 32);
      }
      float a0 = p0 / (s0 + SM_EPS);   // lanes >= deg have a0 = a1 = 0
      float a1 = p1 / (s1 + SM_EPS);
      for (int i = 0; i < deg; i += 8) {
        int e0 = i + ehi, e1 = i + 2 + ehi, e2 = i + 4 + ehi, e3 = i + 6 + ehi;
        int sA = __shfl(sl_, e0, 32);
        int sB = __shfl(sl_, e1, 32);
        int sC = __shfl(sl_, e2, 32);
        int sD = __shfl(sl_, e3, 32);
        float wA0 = __shfl(a0, e0, 32), wA1 = __shfl(a1, e0, 32);
        float wB0 = __shfl(a0, e1, 32), wB1 = __shfl(a1, e1, 32);
        float wC0 = __shfl(a0, e2, 32), wC1 = __shfl(a1, e2, 32);
        float wD0 = __shfl(a0, e3, 32), wD1 = __shfl(a1, e3, 32);
        float wA = hh ? wA1 : wA0, wB = hh ? wB1 : wB0;
        float wC = hh ? wC1 : wC0, wD = hh ? wD1 : wD0;
        half8v gA = *(const half8v*)&G[(size_t)sA * 128 + cc];
        half8v gB = *(const half8v*)&G[(size_t)sB * 128 + cc];
        half8v gC = *(const half8v*)&G[(size_t)sC * 128 + cc];
        half8v gD = *(const half8v*)&G[(size_t)sD * 128 + cc];
        fma8(accP, gA, wA);
        fma8(accQ, gB, wB);
        fma8(accP, gC, wC);
        fma8(accQ, gD, wD);
      }
    } else {
      float s0 = 0.f, s1 = 0.f;
      for (int i = l; i < deg; i += 32) {
        int s = csr_src[beg + i];
        float2 ap = *(const float2*)&als[(size_t)s * 2];
        float v0 = ap.x + adp.x; v0 = v0 > 0.f ? v0 : NEG_SLOPE * v0;
        float v1 = ap.y + adp.y; v1 = v1 > 0.f ? v1 : NEG_SLOPE * v1;
        s0 += __expf(v0); s1 += __expf(v1);
      }
#pragma unroll
      for (int o = 1; o < 32; o <<= 1) {
        s0 += __shfl_xor(s0, o, 32);
        s1 += __shfl_xor(s1, o, 32);
      }
      float inv0 = 1.f / (s0 + SM_EPS);
      float inv1 = 1.f / (s1 + SM_EPS);
      for (int i = 0; i < deg; i += 2) {
        int  e   = i + ehi;
        bool act = e < deg;
        int  sE  = 0;
        float w  = 0.f;
        if (act) {
          sE = csr_src[beg + e];
          float2 ap = *(const float2*)&als[(size_t)sE * 2];
          float v0 = ap.x + adp.x; v0 = v0 > 0.f ? v0 : NEG_SLOPE * v0;
          float v1 = ap.y + adp.y; v1 = v1 > 0.f ? v1 : NEG_SLOPE * v1;
          w = hh ? (__expf(v1) * inv1) : (__expf(v0) * inv0);
        }
        half8v g = *(const half8v*)&G[(size_t)sE * 128 + cc];
        fma8(accP, g, w);
      }
    }
    float o8[8];
#pragma unroll
    for (int k = 0; k < 8; k++) {
      o8[k] = accP[k] + accQ[k];
      o8[k] += __shfl_xor(o8[k], 16, 32);
    }
    if (l < 16) {
      float4 bv0 = *(const float4*)&bias[cc],  bv1 = *(const float4*)&bias[cc + 4];
      float4 mv0 = *(const float4*)&mean[cc],  mv1 = *(const float4*)&mean[cc + 4];
      float4 vv0 = *(const float4*)&var[cc],   vv1 = *(const float4*)&var[cc + 4];
      float4 gv0 = *(const float4*)&gamma[cc], gv1 = *(const float4*)&gamma[cc + 4];
      float4 tv0 = *(const float4*)&beta[cc],  tv1 = *(const float4*)&beta[cc + 4];
      float4 u0, u1;
      u0.x = fmaxf((o8[0] + bv0.x - mv0.x) * rsqrtf(vv0.x + BN_EPS) * gv0.x + tv0.x, 0.f);
      u0.y = fmaxf((o8[1] + bv0.y - mv0.y) * rsqrtf(vv0.y + BN_EPS) * gv0.y + tv0.y, 0.f);
      u0.z = fmaxf((o8[2] + bv0.z - mv0.z) * rsqrtf(vv0.z + BN_EPS) * gv0.z + tv0.z, 0.f);
      u0.w = fmaxf((o8[3] + bv0.w - mv0.w) * rsqrtf(vv0.w + BN_EPS) * gv0.w + tv0.w, 0.f);
      u1.x = fmaxf((o8[4] + bv1.x - mv1.x) * rsqrtf(vv1.x + BN_EPS) * gv1.x + tv1.x, 0.f);
      u1.y = fmaxf((o8[5] + bv1.y - mv1.y) * rsqrtf(vv1.y + BN_EPS) * gv1.y + tv1.y, 0.f);
      u1.z = fmaxf((o8[6] + bv1.z - mv1.z) * rsqrtf(vv1.z + BN_EPS) * gv1.z + tv1.z, 0.f);
      u1.w = fmaxf((o8[7] + bv1.w - mv1.w) * rsqrtf(vv1.w + BN_EPS) * gv1.w + tv1.w, 0.f);
      *(float4*)&out[(size_t)node * 128 + cc]     = u0;
      *(float4*)&out[(size_t)node * 128 + cc + 4] = u1;
    }
  }
}

// ---------- GAT aggregation (H=1): 8 lanes/row, 4 row-loads in flight ----------
__global__ __launch_bounds__(256) void gat_agg1_k(
    const int* __restrict__ rowptr, const uint16_t* __restrict__ csr_src,
    const float* __restrict__ als, const float* __restrict__ ald,
    const __half* __restrict__ G, const float* __restrict__ bias,
    float* __restrict__ out, int n) {
  int l   = threadIdx.x & 31;
  int grp = (blockIdx.x * blockDim.x + threadIdx.x) >> 5;
  int ng  = (gridDim.x * blockDim.x) >> 5;
  int e8  = l >> 3;        // edge slot (0..3)
  int sub = l & 7;         // 8 lanes cover one 64-ch fp16 row
  int cc  = sub * 8;
  for (int node = grp; node < n; node += ng) {
    int beg = rowptr[node];
    int deg = rowptr[node + 1] - beg;
    float ad0 = ald[node];
    float accP[8], accQ[8];
#pragma unroll
    for (int k = 0; k < 8; k++) { accP[k] = 0.f; accQ[k] = 0.f; }
    if (deg <= 32) {
      int sl_ = 0;
      float p0 = 0.f;
      if (l < deg) {
        sl_ = csr_src[beg + l];
        float v0 = als[sl_] + ad0;
        v0 = v0 > 0.f ? v0 : NEG_SLOPE * v0;
        p0 = __expf(v0);
      }
      float s0 = p0;
#pragma unroll
      for (int o = 1; o < 32; o <<= 1) s0 += __shfl_xor(s0, o, 32);
      float a0 = p0 / (s0 + SM_EPS);
      for (int i = 0; i < deg; i += 16) {
        int e0 = i + e8, e1 = i + 4 + e8, e2 = i + 8 + e8, e3 = i + 12 + e8;
        int sA = __shfl(sl_, e0, 32);
        int sB = __shfl(sl_, e1, 32);
        int sC = __shfl(sl_, e2, 32);
        int sD = __shfl(sl_, e3, 32);
        float wA = __shfl(a0, e0, 32);
        float wB = __shfl(a0, e1, 32);
        float wC = __shfl(a0, e2, 32);
        float wD = __shfl(a0, e3, 32);
        half8v gA = *(const half8v*)&G[(size_t)sA * 64 + cc];
        half8v gB = *(const half8v*)&G[(size_t)sB * 64 + cc];
        half8v gC = *(const half8v*)&G[(size_t)sC * 64 + cc];
        half8v gD = *(const half8v*)&G[(size_t)sD * 64 + cc];
        fma8(accP, gA, wA);
        fma8(accQ, gB, wB);
        fma8(accP, gC, wC);
        fma8(accQ, gD, wD);
      }
    } else {
      float s0 = 0.f;
      for (int i = l; i < deg; i += 32) {
        int s = csr_src[beg + i];
        float v0 = als[s] + ad0; v0 = v0 > 0.f ? v0 : NEG_SLOPE * v0;
        s0 += __expf(v0);
      }
#pragma unroll
      for (int o = 1; o < 32; o <<= 1) s0 += __shfl_xor(s0, o, 32);
      float inv0 = 1.f / (s0 + SM_EPS);
      for (int i = 0; i < deg; i += 4) {
        int  e   = i + e8;
        bool act = e < deg;
        int  sE  = 0;
        float w  = 0.f;
        if (act) {
          sE = csr_src[beg + e];
          float v0 = als[sE] + ad0; v0 = v0 > 0.f ? v0 : NEG_SLOPE * v0;
          w = __expf(v0) * inv0;
        }
        half8v g = *(const half8v*)&G[(size_t)sE * 64 + cc];
        fma8(accP, g, w);
      }
    }
    float o8[8];
#pragma unroll
    for (int k = 0; k < 8; k++) {
      o8[k] = accP[k] + accQ[k];
      o8[k] += __shfl_xor(o8[k], 8, 32);
      o8[k] += __shfl_xor(o8[k], 16, 32);
    }
    if (l < 8) {
      float4 bv0 = *(const float4*)&bias[cc], bv1 = *(const float4*)&bias[cc + 4];
      float4 u0 = make_float4(o8[0] + bv0.x, o8[1] + bv0.y, o8[2] + bv0.z, o8[3] + bv0.w);
      float4 u1 = make_float4(o8[4] + bv1.x, o8[5] + bv1.y, o8[6] + bv1.z, o8[7] + bv1.w);
      *(float4*)&out[(size_t)node * 64 + cc]     = u0;
      *(float4*)&out[(size_t)node * 64 + cc + 4] = u1;
    }
  }
}

// =======================================================================
extern "C" void kernel_launch(void* const* d_in, const int* in_sizes, int n_in,
                              void* d_out, int out_size, void* d_ws, size_t ws_size,
                              hipStream_t stream) {
  const float* x   = (const float*)d_in[0];
  const int*   ei  = (const int*)d_in[1];
  const float* W0  = (const float*)d_in[2];
  const float* as0 = (const float*)d_in[3];
  const float* ad0 = (const float*)d_in[4];
  const float* b0  = (const float*)d_in[5];
  const float* gm0 = (const float*)d_in[6];
  const float* bt0 = (const float*)d_in[7];
  const float* mu0 = (const float*)d_in[8];
  const float* vr0 = (const float*)d_in[9];
  const float* W1  = (const float*)d_in[10];
  const float* as1 = (const float*)d_in[11];
  const float* ad1 = (const float*)d_in[12];
  const float* b1  = (const float*)d_in[13];
  const float* gm1 = (const float*)d_in[14];
  const float* bt1 = (const float*)d_in[15];
  const float* mu1 = (const float*)d_in[16];
  const float* vr1 = (const float*)d_in[17];
  const float* W2  = (const float*)d_in[18];
  const float* as2 = (const float*)d_in[19];
  const float* ad2 = (const float*)d_in[20];
  const float* b2  = (const float*)d_in[21];

  int N  = in_sizes[0] / 128;
  int E  = in_sizes[1] / 2;
  int ET = E + N;
  const int* srcp = ei;
  const int* dstp = ei + E;

  char* w = (char*)d_ws;
  auto carve = [&](size_t bytes) {
    void* p = (void*)w;
    w += (bytes + 255) & ~(size_t)255;
    return p;
  };
  __half*   G      = (__half*)carve((size_t)N * 128 * 2);
  float*    Hb     = (float*)carve((size_t)N * 128 * 4);
  float*    ALS    = (float*)carve((size_t)N * 2 * 4);
  float*    ALD    = (float*)carve((size_t)N * 2 * 4);
  int*      DEG    = (int*)carve((size_t)N * 4);
  int*      INCL   = (int*)carve((size_t)N * 4);
  int*      BSUM   = (int*)carve((size_t)64 * 4);
  int*      ROWPTR = (int*)carve((size_t)(N + 1) * 4);
  int*      CURSOR = (int*)carve((size_t)N * 4);
  uint16_t* CSRSRC = (uint16_t*)carve((size_t)ET * 2);

  int egrid = min((ET + 255) / 256, 2048);
  int agrid = (N + 7) / 8;  // 32-lane groups: 8 nodes per 256-thread block
  int nblk  = (N + 1023) / 1024;

  // ---- CSR build (graph shared by all 3 layers) ----
  hipMemsetAsync(DEG, 0, (size_t)N * 4, stream);
  deg_k<<<egrid, 256, 0, stream>>>(dstp, E, N, DEG);
  scan1_k<<<nblk, 1024, 0, stream>>>(DEG, INCL, BSUM, N);
  scan2_k<<<1, 64, 0, stream>>>(BSUM, nblk);
  scan3_k<<<(N + 255) / 256, 256, 0, stream>>>(INCL, BSUM, DEG, ROWPTR, CURSOR, N);
  csr_fill_k<<<egrid, 256, 0, stream>>>(srcp, dstp, E, N, CURSOR, CSRSRC);
  csr_canon_k<<<agrid, 256, 0, stream>>>(ROWPTR, CSRSRC, N);

  // ---------------- layer 0 ----------------
  gemm_k<128, 128, 2><<<512, 256, 0, stream>>>(x, W0, as0, ad0, G, ALS, ALD, N);
  gat_agg2_k<<<agrid, 256, 0, stream>>>(ROWPTR, CSRSRC, ALS, ALD, G, b0, gm0, bt0,
                                        mu0, vr0, Hb, N);
  // ---------------- layer 1 ----------------
  gemm_k<128, 128, 2><<<512, 256, 0, stream>>>(Hb, W1, as1, ad1, G, ALS, ALD, N);
  gat_agg2_k<<<agrid, 256, 0, stream>>>(ROWPTR, CSRSRC, ALS, ALD, G, b1, gm1, bt1,
                                        mu1, vr1, Hb, N);
  // ---------------- layer 2 ----------------
  gemm_k<128, 64, 1><<<512, 256, 0, stream>>>(Hb, W2, as2, ad2, G, ALS, ALD, N);
  gat_agg1_k<<<agrid, 256, 0, stream>>>(ROWPTR, CSRSRC, ALS, ALD, G, b2,
                                        (float*)d_out, N);
}

// Round 12
// 311.395 us; speedup vs baseline: 2.6322x; 1.0004x over previous
//
#include <hip/hip_runtime.h>
#include <hip/hip_fp16.h>
#include <cstdint>

#define NEG_SLOPE 0.2f
#define SM_EPS 1e-16f
#define BN_EPS 1e-5f

struct alignas(8)  half4v { __half2 lo, hi; };
struct alignas(16) half8v { __half2 h0, h1, h2, h3; };

__device__ __forceinline__ void fma8(float* acc, const half8v& g, float w) {
  float2 f0 = __half22float2(g.h0), f1 = __half22float2(g.h1);
  float2 f2 = __half22float2(g.h2), f3 = __half22float2(g.h3);
  acc[0] = fmaf(w, f0.x, acc[0]); acc[1] = fmaf(w, f0.y, acc[1]);
  acc[2] = fmaf(w, f1.x, acc[2]); acc[3] = fmaf(w, f1.y, acc[3]);
  acc[4] = fmaf(w, f2.x, acc[4]); acc[5] = fmaf(w, f2.y, acc[5]);
  acc[6] = fmaf(w, f3.x, acc[6]); acc[7] = fmaf(w, f3.y, acc[7]);
}

// ---------- GEMM + fused attention coefficients, 4 rows/thread, fp16 G out ----------
template <int INC, int OUTC, int H>
__global__ __launch_bounds__(256) void gemm_k(const float* __restrict__ A,
                                              const float* __restrict__ W,
                                              const float* __restrict__ asrc,
                                              const float* __restrict__ adst,
                                              __half* __restrict__ G,
                                              float* __restrict__ als,
                                              float* __restrict__ ald, int nrows) {
  constexpr int TPR  = OUTC / 4;
  constexpr int RS   = 256 / TPR;
  constexpr int ROWS = RS * 4;
  __shared__ float wl[INC * OUTC];
  __shared__ float hl[ROWS * INC];
  for (int i = threadIdx.x * 4; i < INC * OUTC; i += 1024)
    *(float4*)&wl[i] = *(const float4*)&W[i];
  int r  = threadIdx.x / TPR;
  int c0 = (threadIdx.x % TPR) * 4;
  float4 sv = *(const float4*)&asrc[c0];
  float4 dv = *(const float4*)&adst[c0];
  for (int base = blockIdx.x * ROWS; base < nrows; base += gridDim.x * ROWS) {
    __syncthreads();
    int limit = min(ROWS, nrows - base) * INC;
    for (int i = threadIdx.x * 4; i < limit; i += 1024)
      *(float4*)&hl[i] = *(const float4*)&A[(size_t)base * INC + i];
    __syncthreads();
    float acc[4][4];
#pragma unroll
    for (int q = 0; q < 4; q++)
#pragma unroll
      for (int c = 0; c < 4; c++) acc[q][c] = 0.f;
#pragma unroll 8
    for (int k = 0; k < INC; k++) {
      float4 wv = *(float4*)&wl[k * OUTC + c0];
#pragma unroll
      for (int q = 0; q < 4; q++) {
        float h = hl[(r + q * RS) * INC + k];
        acc[q][0] = fmaf(h, wv.x, acc[q][0]);
        acc[q][1] = fmaf(h, wv.y, acc[q][1]);
        acc[q][2] = fmaf(h, wv.z, acc[q][2]);
        acc[q][3] = fmaf(h, wv.w, acc[q][3]);
      }
    }
    float ps[4], pd[4];
#pragma unroll
    for (int q = 0; q < 4; q++) {
      int rq = base + r + q * RS;
      if (rq < nrows) {
        half4v hv;
        hv.lo = __floats2half2_rn(acc[q][0], acc[q][1]);
        hv.hi = __floats2half2_rn(acc[q][2], acc[q][3]);
        *(half4v*)&G[(size_t)rq * OUTC + c0] = hv;
      }
      ps[q] = acc[q][0] * sv.x + acc[q][1] * sv.y + acc[q][2] * sv.z + acc[q][3] * sv.w;
      pd[q] = acc[q][0] * dv.x + acc[q][1] * dv.y + acc[q][2] * dv.z + acc[q][3] * dv.w;
    }
#pragma unroll
    for (int o = 1; o < 16; o <<= 1) {
#pragma unroll
      for (int q = 0; q < 4; q++) {
        ps[q] += __shfl_xor(ps[q], o);
        pd[q] += __shfl_xor(pd[q], o);
      }
    }
    if ((threadIdx.x & 15) == 0) {
      int head = c0 >> 6;
#pragma unroll
      for (int q = 0; q < 4; q++) {
        int rq = base + r + q * RS;
        if (rq < nrows) {
          als[(size_t)rq * H + head] = ps[q];
          ald[(size_t)rq * H + head] = pd[q];
        }
      }
    }
  }
}

// ---------- CSR build (XCD-local scatter) ----------
// Blocks are grouped by blockIdx.x & 7 (round-robin block->XCD heuristic); group g
// owns node range [g*npg, (g+1)*npg). Each group scans the FULL edge stream but
// performs atomics/stores only for its own range, so deg/cursor/CSR cache lines
// are touched by one XCD only. Correctness depends only on the range partition.
__global__ __launch_bounds__(256) void deg_k(const int* __restrict__ dst, int E_,
                                             int n, int* __restrict__ deg) {
  int g   = blockIdx.x & 7;
  int npg = (n + 7) / 8;
  int n0  = g * npg;
  int n1  = min(n0 + npg, n);
  int bg  = blockIdx.x >> 3;
  int nbg = gridDim.x >> 3;
  int ET  = E_ + n;
  for (int e = bg * 256 + threadIdx.x; e < ET; e += nbg * 256) {
    int dN = (e < E_) ? dst[e] : (e - E_);
    if (dN >= n0 && dN < n1) atomicAdd(&deg[dN], 1);
  }
}

__global__ __launch_bounds__(1024) void scan1_k(const int* __restrict__ deg,
                                                int* __restrict__ incl,
                                                int* __restrict__ bsum, int n) {
  __shared__ int sm[1024];
  int i = blockIdx.x * 1024 + threadIdx.x;
  int v = (i < n) ? deg[i] : 0;
  sm[threadIdx.x] = v;
  __syncthreads();
#pragma unroll
  for (int o = 1; o < 1024; o <<= 1) {
    int t = (threadIdx.x >= o) ? sm[threadIdx.x - o] : 0;
    __syncthreads();
    sm[threadIdx.x] += t;
    __syncthreads();
  }
  if (i < n) incl[i] = sm[threadIdx.x];
  if (threadIdx.x == 1023) bsum[blockIdx.x] = sm[1023];
}

__global__ void scan2_k(int* __restrict__ bsum, int nb) {
  int lane = threadIdx.x;
  int v = (lane < nb) ? bsum[lane] : 0;
#pragma unroll
  for (int o = 1; o < 64; o <<= 1) {
    int t = __shfl_up(v, o);
    if (lane >= o) v += t;
  }
  if (lane < nb) bsum[lane] = v;
}

__global__ void scan3_k(const int* __restrict__ incl, const int* __restrict__ bsum,
                        const int* __restrict__ deg, int* __restrict__ rowptr,
                        int* __restrict__ cursor, int n) {
  int i = blockIdx.x * blockDim.x + threadIdx.x;
  if (i < n) {
    int blk = i >> 10;
    int off = blk ? bsum[blk - 1] : 0;
    int r = incl[i] + off;
    rowptr[i + 1] = r;
    cursor[i] = r - deg[i];
  }
  if (i == 0) rowptr[0] = 0;
}

__global__ __launch_bounds__(256) void csr_fill_k(const int* __restrict__ src,
                                                  const int* __restrict__ dst, int E_,
                                                  int n, int* __restrict__ cursor,
                                                  uint16_t* __restrict__ csr_src) {
  int g   = blockIdx.x & 7;
  int npg = (n + 7) / 8;
  int n0  = g * npg;
  int n1  = min(n0 + npg, n);
  int bg  = blockIdx.x >> 3;
  int nbg = gridDim.x >> 3;
  int ET  = E_ + n;
  for (int e = bg * 256 + threadIdx.x; e < ET; e += nbg * 256) {
    int dN = (e < E_) ? dst[e] : (e - E_);
    if (dN >= n0 && dN < n1) {
      int sN  = (e < E_) ? src[e] : dN;
      int pos = atomicAdd(&cursor[dN], 1);
      csr_src[pos] = (uint16_t)sN;
    }
  }
}

// canonicalize: in-place rank-permutation sort of each dst segment by src id.
__global__ __launch_bounds__(256) void csr_canon_k(const int* __restrict__ rowptr,
                                                   uint16_t* __restrict__ csr, int n) {
  int l   = threadIdx.x & 31;
  int grp = (blockIdx.x * blockDim.x + threadIdx.x) >> 5;
  int ng  = (gridDim.x * blockDim.x) >> 5;
  for (int node = grp; node < n; node += ng) {
    int beg = rowptr[node];
    int deg = rowptr[node + 1] - beg;
    if (deg <= 1) continue;
    if (deg <= 128) {
      int iters = (deg + 31) >> 5;
      uint16_t v[4];
      int      rk[4];
#pragma unroll
      for (int m = 0; m < 4; m++) {
        if (m >= iters) break;
        int  i   = l + m * 32;
        bool act = i < deg;
        uint16_t vi = act ? csr[beg + i] : (uint16_t)0;
        int rank = 0;
        for (int j = 0; j < deg; j++) {
          uint16_t vj = csr[beg + j];
          rank += (int)((vj < vi) | ((vj == vi) & (j < i)));
        }
        v[m]  = vi;
        rk[m] = act ? rank : -1;
      }
#pragma unroll
      for (int m = 0; m < 4; m++) {
        if (m >= iters) break;
        if (rk[m] >= 0) csr[beg + rk[m]] = v[m];
      }
    } else if (l == 0) {
      for (int i = beg + 1; i < beg + deg; ++i) {
        uint16_t vv = csr[i];
        int j = i - 1;
        while (j >= beg && csr[j] > vv) { csr[j + 1] = csr[j]; --j; }
        csr[j + 1] = vv;
      }
    }
  }
}

// ---------- fused GAT aggregation (H=2): 16 lanes/row, 4 row-loads in flight ----------
__global__ __launch_bounds__(256) void gat_agg2_k(
    const int* __restrict__ rowptr, const uint16_t* __restrict__ csr_src,
    const float* __restrict__ als, const float* __restrict__ ald,
    const __half* __restrict__ G, const float* __restrict__ bias,
    const float* __restrict__ gamma, const float* __restrict__ beta,
    const float* __restrict__ mean, const float* __restrict__ var,
    float* __restrict__ out, int n) {
  int l   = threadIdx.x & 31;
  int grp = (blockIdx.x * blockDim.x + threadIdx.x) >> 5;
  int ng  = (gridDim.x * blockDim.x) >> 5;
  int ehi = l >> 4;
  int sub = l & 15;
  int cc  = sub * 8;
  bool hh = sub >= 8;
  for (int node = grp; node < n; node += ng) {
    int beg = rowptr[node];
    int deg = rowptr[node + 1] - beg;
    float2 adp = *(const float2*)&ald[(size_t)node * 2];
    float accP[8], accQ[8];
#pragma unroll
    for (int k = 0; k < 8; k++) { accP[k] = 0.f; accQ[k] = 0.f; }
    if (deg <= 32) {
      int sl_ = 0;
      float p0 = 0.f, p1 = 0.f;
      if (l < deg) {
        sl_ = csr_src[beg + l];
        float2 ap = *(const float2*)&als[(size_t)sl_ * 2];
        float v0 = ap.x + adp.x, v1 = ap.y + adp.y;
        v0 = v0 > 0.f ? v0 : NEG_SLOPE * v0;
        v1 = v1 > 0.f ? v1 : NEG_SLOPE * v1;
        p0 = __expf(v0); p1 = __expf(v1);
      }
      float s0 = p0, s1 = p1;
#pragma unroll
      for (int o = 1; o < 32; o <<= 1) {
        s0 += __shfl_xor(s0, o, 32);
        s1 += __shfl_xor(s1, o, 32);
      }
      float a0 = p0 / (s0 + SM_EPS);
      float a1 = p1 / (s1 + SM_EPS);
      for (int i = 0; i < deg; i += 8) {
        int e0 = i + ehi, e1 = i + 2 + ehi, e2 = i + 4 + ehi, e3 = i + 6 + ehi;
        int sA = __shfl(sl_, e0, 32);
        int sB = __shfl(sl_, e1, 32);
        int sC = __shfl(sl_, e2, 32);
        int sD = __shfl(sl_, e3, 32);
        float wA0 = __shfl(a0, e0, 32), wA1 = __shfl(a1, e0, 32);
        float wB0 = __shfl(a0, e1, 32), wB1 = __shfl(a1, e1, 32);
        float wC0 = __shfl(a0, e2, 32), wC1 = __shfl(a1, e2, 32);
        float wD0 = __shfl(a0, e3, 32), wD1 = __shfl(a1, e3, 32);
        float wA = hh ? wA1 : wA0, wB = hh ? wB1 : wB0;
        float wC = hh ? wC1 : wC0, wD = hh ? wD1 : wD0;
        half8v gA = *(const half8v*)&G[(size_t)sA * 128 + cc];
        half8v gB = *(const half8v*)&G[(size_t)sB * 128 + cc];
        half8v gC = *(const half8v*)&G[(size_t)sC * 128 + cc];
        half8v gD = *(const half8v*)&G[(size_t)sD * 128 + cc];
        fma8(accP, gA, wA);
        fma8(accQ, gB, wB);
        fma8(accP, gC, wC);
        fma8(accQ, gD, wD);
      }
    } else {
      float s0 = 0.f, s1 = 0.f;
      for (int i = l; i < deg; i += 32) {
        int s = csr_src[beg + i];
        float2 ap = *(const float2*)&als[(size_t)s * 2];
        float v0 = ap.x + adp.x; v0 = v0 > 0.f ? v0 : NEG_SLOPE * v0;
        float v1 = ap.y + adp.y; v1 = v1 > 0.f ? v1 : NEG_SLOPE * v1;
        s0 += __expf(v0); s1 += __expf(v1);
      }
#pragma unroll
      for (int o = 1; o < 32; o <<= 1) {
        s0 += __shfl_xor(s0, o, 32);
        s1 += __shfl_xor(s1, o, 32);
      }
      float inv0 = 1.f / (s0 + SM_EPS);
      float inv1 = 1.f / (s1 + SM_EPS);
      for (int i = 0; i < deg; i += 2) {
        int  e   = i + ehi;
        bool act = e < deg;
        int  sE  = 0;
        float w  = 0.f;
        if (act) {
          sE = csr_src[beg + e];
          float2 ap = *(const float2*)&als[(size_t)sE * 2];
          float v0 = ap.x + adp.x; v0 = v0 > 0.f ? v0 : NEG_SLOPE * v0;
          float v1 = ap.y + adp.y; v1 = v1 > 0.f ? v1 : NEG_SLOPE * v1;
          w = hh ? (__expf(v1) * inv1) : (__expf(v0) * inv0);
        }
        half8v g = *(const half8v*)&G[(size_t)sE * 128 + cc];
        fma8(accP, g, w);
      }
    }
    float o8[8];
#pragma unroll
    for (int k = 0; k < 8; k++) {
      o8[k] = accP[k] + accQ[k];
      o8[k] += __shfl_xor(o8[k], 16, 32);
    }
    if (l < 16) {
      float4 bv0 = *(const float4*)&bias[cc],  bv1 = *(const float4*)&bias[cc + 4];
      float4 mv0 = *(const float4*)&mean[cc],  mv1 = *(const float4*)&mean[cc + 4];
      float4 vv0 = *(const float4*)&var[cc],   vv1 = *(const float4*)&var[cc + 4];
      float4 gv0 = *(const float4*)&gamma[cc], gv1 = *(const float4*)&gamma[cc + 4];
      float4 tv0 = *(const float4*)&beta[cc],  tv1 = *(const float4*)&beta[cc + 4];
      float4 u0, u1;
      u0.x = fmaxf((o8[0] + bv0.x - mv0.x) * rsqrtf(vv0.x + BN_EPS) * gv0.x + tv0.x, 0.f);
      u0.y = fmaxf((o8[1] + bv0.y - mv0.y) * rsqrtf(vv0.y + BN_EPS) * gv0.y + tv0.y, 0.f);
      u0.z = fmaxf((o8[2] + bv0.z - mv0.z) * rsqrtf(vv0.z + BN_EPS) * gv0.z + tv0.z, 0.f);
      u0.w = fmaxf((o8[3] + bv0.w - mv0.w) * rsqrtf(vv0.w + BN_EPS) * gv0.w + tv0.w, 0.f);
      u1.x = fmaxf((o8[4] + bv1.x - mv1.x) * rsqrtf(vv1.x + BN_EPS) * gv1.x + tv1.x, 0.f);
      u1.y = fmaxf((o8[5] + bv1.y - mv1.y) * rsqrtf(vv1.y + BN_EPS) * gv1.y + tv1.y, 0.f);
      u1.z = fmaxf((o8[6] + bv1.z - mv1.z) * rsqrtf(vv1.z + BN_EPS) * gv1.z + tv1.z, 0.f);
      u1.w = fmaxf((o8[7] + bv1.w - mv1.w) * rsqrtf(vv1.w + BN_EPS) * gv1.w + tv1.w, 0.f);
      *(float4*)&out[(size_t)node * 128 + cc]     = u0;
      *(float4*)&out[(size_t)node * 128 + cc + 4] = u1;
    }
  }
}

// ---------- GAT aggregation (H=1): 8 lanes/row, 4 row-loads in flight ----------
__global__ __launch_bounds__(256) void gat_agg1_k(
    const int* __restrict__ rowptr, const uint16_t* __restrict__ csr_src,
    const float* __restrict__ als, const float* __restrict__ ald,
    const __half* __restrict__ G, const float* __restrict__ bias,
    float* __restrict__ out, int n) {
  int l   = threadIdx.x & 31;
  int grp = (blockIdx.x * blockDim.x + threadIdx.x) >> 5;
  int ng  = (gridDim.x * blockDim.x) >> 5;
  int e8  = l >> 3;
  int sub = l & 7;
  int cc  = sub * 8;
  for (int node = grp; node < n; node += ng) {
    int beg = rowptr[node];
    int deg = rowptr[node + 1] - beg;
    float ad0 = ald[node];
    float accP[8], accQ[8];
#pragma unroll
    for (int k = 0; k < 8; k++) { accP[k] = 0.f; accQ[k] = 0.f; }
    if (deg <= 32) {
      int sl_ = 0;
      float p0 = 0.f;
      if (l < deg) {
        sl_ = csr_src[beg + l];
        float v0 = als[sl_] + ad0;
        v0 = v0 > 0.f ? v0 : NEG_SLOPE * v0;
        p0 = __expf(v0);
      }
      float s0 = p0;
#pragma unroll
      for (int o = 1; o < 32; o <<= 1) s0 += __shfl_xor(s0, o, 32);
      float a0 = p0 / (s0 + SM_EPS);
      for (int i = 0; i < deg; i += 16) {
        int e0 = i + e8, e1 = i + 4 + e8, e2 = i + 8 + e8, e3 = i + 12 + e8;
        int sA = __shfl(sl_, e0, 32);
        int sB = __shfl(sl_, e1, 32);
        int sC = __shfl(sl_, e2, 32);
        int sD = __shfl(sl_, e3, 32);
        float wA = __shfl(a0, e0, 32);
        float wB = __shfl(a0, e1, 32);
        float wC = __shfl(a0, e2, 32);
        float wD = __shfl(a0, e3, 32);
        half8v gA = *(const half8v*)&G[(size_t)sA * 64 + cc];
        half8v gB = *(const half8v*)&G[(size_t)sB * 64 + cc];
        half8v gC = *(const half8v*)&G[(size_t)sC * 64 + cc];
        half8v gD = *(const half8v*)&G[(size_t)sD * 64 + cc];
        fma8(accP, gA, wA);
        fma8(accQ, gB, wB);
        fma8(accP, gC, wC);
        fma8(accQ, gD, wD);
      }
    } else {
      float s0 = 0.f;
      for (int i = l; i < deg; i += 32) {
        int s = csr_src[beg + i];
        float v0 = als[s] + ad0; v0 = v0 > 0.f ? v0 : NEG_SLOPE * v0;
        s0 += __expf(v0);
      }
#pragma unroll
      for (int o = 1; o < 32; o <<= 1) s0 += __shfl_xor(s0, o, 32);
      float inv0 = 1.f / (s0 + SM_EPS);
      for (int i = 0; i < deg; i += 4) {
        int  e   = i + e8;
        bool act = e < deg;
        int  sE  = 0;
        float w  = 0.f;
        if (act) {
          sE = csr_src[beg + e];
          float v0 = als[sE] + ad0; v0 = v0 > 0.f ? v0 : NEG_SLOPE * v0;
          w = __expf(v0) * inv0;
        }
        half8v g = *(const half8v*)&G[(size_t)sE * 64 + cc];
        fma8(accP, g, w);
      }
    }
    float o8[8];
#pragma unroll
    for (int k = 0; k < 8; k++) {
      o8[k] = accP[k] + accQ[k];
      o8[k] += __shfl_xor(o8[k], 8, 32);
      o8[k] += __shfl_xor(o8[k], 16, 32);
    }
    if (l < 8) {
      float4 bv0 = *(const float4*)&bias[cc], bv1 = *(const float4*)&bias[cc + 4];
      float4 u0 = make_float4(o8[0] + bv0.x, o8[1] + bv0.y, o8[2] + bv0.z, o8[3] + bv0.w);
      float4 u1 = make_float4(o8[4] + bv1.x, o8[5] + bv1.y, o8[6] + bv1.z, o8[7] + bv1.w);
      *(float4*)&out[(size_t)node * 64 + cc]     = u0;
      *(float4*)&out[(size_t)node * 64 + cc + 4] = u1;
    }
  }
}

// =======================================================================
extern "C" void kernel_launch(void* const* d_in, const int* in_sizes, int n_in,
                              void* d_out, int out_size, void* d_ws, size_t ws_size,
                              hipStream_t stream) {
  const float* x   = (const float*)d_in[0];
  const int*   ei  = (const int*)d_in[1];
  const float* W0  = (const float*)d_in[2];
  const float* as0 = (const float*)d_in[3];
  const float* ad0 = (const float*)d_in[4];
  const float* b0  = (const float*)d_in[5];
  const float* gm0 = (const float*)d_in[6];
  const float* bt0 = (const float*)d_in[7];
  const float* mu0 = (const float*)d_in[8];
  const float* vr0 = (const float*)d_in[9];
  const float* W1  = (const float*)d_in[10];
  const float* as1 = (const float*)d_in[11];
  const float* ad1 = (const float*)d_in[12];
  const float* b1  = (const float*)d_in[13];
  const float* gm1 = (const float*)d_in[14];
  const float* bt1 = (const float*)d_in[15];
  const float* mu1 = (const float*)d_in[16];
  const float* vr1 = (const float*)d_in[17];
  const float* W2  = (const float*)d_in[18];
  const float* as2 = (const float*)d_in[19];
  const float* ad2 = (const float*)d_in[20];
  const float* b2  = (const float*)d_in[21];

  int N  = in_sizes[0] / 128;
  int E  = in_sizes[1] / 2;
  int ET = E + N;
  const int* srcp = ei;
  const int* dstp = ei + E;

  char* w = (char*)d_ws;
  auto carve = [&](size_t bytes) {
    void* p = (void*)w;
    w += (bytes + 255) & ~(size_t)255;
    return p;
  };
  __half*   G      = (__half*)carve((size_t)N * 128 * 2);
  float*    Hb     = (float*)carve((size_t)N * 128 * 4);
  float*    ALS    = (float*)carve((size_t)N * 2 * 4);
  float*    ALD    = (float*)carve((size_t)N * 2 * 4);
  int*      DEG    = (int*)carve((size_t)N * 4);
  int*      INCL   = (int*)carve((size_t)N * 4);
  int*      BSUM   = (int*)carve((size_t)64 * 4);
  int*      ROWPTR = (int*)carve((size_t)(N + 1) * 4);
  int*      CURSOR = (int*)carve((size_t)N * 4);
  uint16_t* CSRSRC = (uint16_t*)carve((size_t)ET * 2);

  int agrid = (N + 7) / 8;  // 32-lane groups: 8 nodes per 256-thread block
  int nblk  = (N + 1023) / 1024;

  // ---- CSR build (graph shared by all 3 layers) ----
  hipMemsetAsync(DEG, 0, (size_t)N * 4, stream);
  deg_k<<<2048, 256, 0, stream>>>(dstp, E, N, DEG);
  scan1_k<<<nblk, 1024, 0, stream>>>(DEG, INCL, BSUM, N);
  scan2_k<<<1, 64, 0, stream>>>(BSUM, nblk);
  scan3_k<<<(N + 255) / 256, 256, 0, stream>>>(INCL, BSUM, DEG, ROWPTR, CURSOR, N);
  csr_fill_k<<<2048, 256, 0, stream>>>(srcp, dstp, E, N, CURSOR, CSRSRC);
  csr_canon_k<<<agrid, 256, 0, stream>>>(ROWPTR, CSRSRC, N);

  // ---------------- layer 0 ----------------
  gemm_k<128, 128, 2><<<512, 256, 0, stream>>>(x, W0, as0, ad0, G, ALS, ALD, N);
  gat_agg2_k<<<agrid, 256, 0, stream>>>(ROWPTR, CSRSRC, ALS, ALD, G, b0, gm0, bt0,
                                        mu0, vr0, Hb, N);
  // ---------------- layer 1 ----------------
  gemm_k<128, 128, 2><<<512, 256, 0, stream>>>(Hb, W1, as1, ad1, G, ALS, ALD, N);
  gat_agg2_k<<<agrid, 256, 0, stream>>>(ROWPTR, CSRSRC, ALS, ALD, G, b1, gm1, bt1,
                                        mu1, vr1, Hb, N);
  // ---------------- layer 2 ----------------
  gemm_k<128, 64, 1><<<512, 256, 0, stream>>>(Hb, W2, as2, ad2, G, ALS, ALD, N);
  gat_agg1_k<<<agrid, 256, 0, stream>>>(ROWPTR, CSRSRC, ALS, ALD, G, b2,
                                        (float*)d_out, N);
}